// Round 6
// baseline (634.247 us; speedup 1.0000x reference)
//
#include <hip/hip_runtime.h>

#define NN 50000
#define NE 800000
#define NG 128
#define NC 41
#define NGRP 3125          // NN/16 node-groups (16 nodes per wave)
#define GCAP 768           // edges per group capacity (mean 256, +32 sd)
#define NCH2 16            // chunk slots per group (13 used: src>>12)

typedef __attribute__((ext_vector_type(8))) short bfrag8;
typedef __attribute__((ext_vector_type(4))) float facc4;

__device__ __forceinline__ float bf2f(unsigned short u) {
  union { unsigned int i; float f; } v; v.i = ((unsigned int)u) << 16; return v.f;
}
__device__ __forceinline__ unsigned short f2bf(float f) {
  union { float f; unsigned int i; } v; v.f = f;
  unsigned int x = v.i;
  x += 0x7fffu + ((x >> 16) & 1u);
  return (unsigned short)(x >> 16);
}
__device__ __forceinline__ unsigned int pack2(float lo, float hi) {
  return (unsigned int)f2bf(lo) | ((unsigned int)f2bf(hi) << 16);
}

// Weights -> bf16, BN affine precompute (applied AFTER relu).
__global__ void prep_kernel(const float* __restrict__ W1, const float* __restrict__ W2,
                            const float* __restrict__ oW1, const float* __restrict__ oW2,
                            const float* __restrict__ gamma, const float* __restrict__ beta,
                            const float* __restrict__ mean, const float* __restrict__ var,
                            unsigned short* W1b, unsigned short* W2b,
                            unsigned short* oW1b, unsigned short* oW2b,
                            float* scale, float* shift) {
  int i = blockIdx.x * 256 + threadIdx.x;
  if (i < 128 * 128) {
    W1b[i] = f2bf(W1[i]);
    W2b[i] = f2bf(W2[i]);
    oW1b[i] = f2bf(oW1[i]);
    oW2b[i] = f2bf(oW2[i]);
  }
  if (i < 128) {
    float s = gamma[i] * rsqrtf(var[i] + 1e-5f);
    scale[i] = s;
    shift[i] = beta[i] - mean[i] * s;
  }
}

// x = emb[node_ids], stored bf16. One thread per 4 feats.
__global__ void embed_kernel(const int* __restrict__ node_ids, const float* __restrict__ emb,
                             unsigned short* __restrict__ xb) {
  int idx = blockIdx.x * 256 + threadIdx.x;
  if (idx >= NN * 32) return;
  int node = idx >> 5, f = (idx & 31) * 4;
  const float4 v = *(const float4*)&emb[node_ids[node] * 128 + f];
  ushort4 o;
  o.x = f2bf(v.x); o.y = f2bf(v.y); o.z = f2bf(v.z); o.w = f2bf(v.w);
  *(ushort4*)&xb[node * 128 + f] = o;
}

// ---- Chunk-sorted per-group edge list build (r4) ----
// count: histogram edges per (dst-group, src-chunk).
__global__ __launch_bounds__(256) void count_kernel(const int* __restrict__ ei,
                                                    int* __restrict__ cnt2) {
  int e = blockIdx.x * 256 + threadIdx.x;
  if (e >= NE) return;
  int d = ei[NE + e];
  int s = ei[e];
  atomicAdd(&cnt2[(d >> 4) * NCH2 + (s >> 12)], 1);
}

// scan: per-group exclusive prefix over the chunk counts -> write cursors,
// store total.
__global__ __launch_bounds__(256) void scan_kernel(const int* __restrict__ cnt2,
                                                   int* __restrict__ cur,
                                                   int* __restrict__ tot) {
  int g = blockIdx.x * 256 + threadIdx.x;
  if (g >= NGRP) return;
  int s = 0;
#pragma unroll
  for (int c = 0; c < NCH2; ++c) {
    int v = cnt2[g * NCH2 + c];
    cur[g * NCH2 + c] = s;
    s += v;
  }
  tot[g] = s > GCAP ? GCAP : s;
}

// place: scatter packed (src<<4 | dstSlot) words into chunk-ordered segments.
__global__ __launch_bounds__(256) void place_kernel(const int* __restrict__ ei,
                                                    int* __restrict__ cur,
                                                    unsigned int* __restrict__ elist) {
  int e = blockIdx.x * 256 + threadIdx.x;
  if (e >= NE) return;
  int d = ei[NE + e];
  int s = ei[e];
  int g = d >> 4;
  int pos = atomicAdd(&cur[g * NCH2 + (s >> 12)], 1);
  if (pos < GCAP)
    elist[(size_t)g * GCAP + pos] = ((unsigned int)s << 4) | (unsigned int)(d & 15);
}

__device__ __forceinline__ void lds_acc2(float2* hbase, unsigned int w, unsigned int d) {
  float2* hp = hbase + (w & 15) * 64;   // 64 float2 = one 128-feat row
  float2 c = *hp;
  c.x += bf2f((unsigned short)(d & 0xffff));
  c.y += bf2f((unsigned short)(d >> 16));
  *hp = c;
}

// Fused GIN layer (r4): chunk-sorted streaming gather into fp32 LDS tile.
//  - Each wave owns 16 dst rows (one group). It walks the group's edge list
//    (physically ordered by 1MB src chunk) in 16-deep batches: one wave-level
//    global_load_dword per edge reads the full 256B src row (64 lanes x 4B),
//    accumulated into hF[row][feat] fp32 LDS (wave-private rows, no atomics).
//  - All ~768 blocks are co-resident -> soft convoy: every XCD's L2 holds the
//    current ~1-2MB chunk window -> gather misses become L2 hits. This attacks
//    the measured MSHR(~16/CU) x latency bound (r1/r3 nulls proved concurrency
//    is capped; r2 proved locality moves FETCH but shallow batches kill it).
//  - No per-node degree divergence: wave edge count ~256+-16.
//  - hF (32KB) is reused as sW for the GEMMs; sA 16KB; 48KB -> 3 blocks/CU.
__global__ __launch_bounds__(256) void gin_layer_kernel(
    const unsigned short* __restrict__ xin,
    const unsigned int* __restrict__ elist,
    const int* __restrict__ gtot,
    const unsigned short* __restrict__ W1b,
    const unsigned short* __restrict__ W2b,
    const float* __restrict__ bias1,
    const float* __restrict__ bias2,
    const float* __restrict__ scale,
    const float* __restrict__ shift,
    unsigned short* __restrict__ Out,
    const int* __restrict__ batch,
    float* __restrict__ pooled,
    int M, int mode, int doPool) {
  __shared__ float hF[64 * 128];             // 32KB fp32 accumulator, then sW
  __shared__ unsigned short sA[64 * 128];    // 16KB
  int tid = threadIdx.x;
  int bRow = blockIdx.x * 64;
  int wave = tid >> 6;
  int lane = tid & 63;

  // ---- Gather: wave-private streaming aggregation ----
  {
    int grp = blockIdx.x * 4 + wave;
    int base = grp * 16;
    int l2 = lane * 2;
    // self-init hF rows (zeros for OOB rows)
#pragma unroll 1
    for (int s = 0; s < 16; ++s) {
      int node = base + s;
      float2 c = {0.f, 0.f};
      if (node < M) {
        unsigned int u = *(const unsigned int*)&xin[node * 128 + l2];
        c.x = bf2f((unsigned short)(u & 0xffff));
        c.y = bf2f((unsigned short)(u >> 16));
      }
      *(float2*)&hF[(wave * 16 + s) * 128 + l2] = c;
    }
    if (base < M) {
      int ecnt = gtot[grp];
      const unsigned int* lst = &elist[(size_t)grp * GCAP];
      float2* hbase = (float2*)&hF[wave * 16 * 128 + l2];
      int j = 0;
#pragma unroll 1
      for (; j + 16 <= ecnt; j += 16) {
        uint4 wa = *(const uint4*)&lst[j];
        uint4 wb = *(const uint4*)&lst[j + 4];
        uint4 wc = *(const uint4*)&lst[j + 8];
        uint4 wd = *(const uint4*)&lst[j + 12];
        unsigned int d0  = *(const unsigned int*)&xin[(wa.x >> 4) * 128 + l2];
        unsigned int d1  = *(const unsigned int*)&xin[(wa.y >> 4) * 128 + l2];
        unsigned int d2  = *(const unsigned int*)&xin[(wa.z >> 4) * 128 + l2];
        unsigned int d3  = *(const unsigned int*)&xin[(wa.w >> 4) * 128 + l2];
        unsigned int d4  = *(const unsigned int*)&xin[(wb.x >> 4) * 128 + l2];
        unsigned int d5  = *(const unsigned int*)&xin[(wb.y >> 4) * 128 + l2];
        unsigned int d6  = *(const unsigned int*)&xin[(wb.z >> 4) * 128 + l2];
        unsigned int d7  = *(const unsigned int*)&xin[(wb.w >> 4) * 128 + l2];
        unsigned int d8  = *(const unsigned int*)&xin[(wc.x >> 4) * 128 + l2];
        unsigned int d9  = *(const unsigned int*)&xin[(wc.y >> 4) * 128 + l2];
        unsigned int d10 = *(const unsigned int*)&xin[(wc.z >> 4) * 128 + l2];
        unsigned int d11 = *(const unsigned int*)&xin[(wc.w >> 4) * 128 + l2];
        unsigned int d12 = *(const unsigned int*)&xin[(wd.x >> 4) * 128 + l2];
        unsigned int d13 = *(const unsigned int*)&xin[(wd.y >> 4) * 128 + l2];
        unsigned int d14 = *(const unsigned int*)&xin[(wd.z >> 4) * 128 + l2];
        unsigned int d15 = *(const unsigned int*)&xin[(wd.w >> 4) * 128 + l2];
        lds_acc2(hbase, wa.x, d0);  lds_acc2(hbase, wa.y, d1);
        lds_acc2(hbase, wa.z, d2);  lds_acc2(hbase, wa.w, d3);
        lds_acc2(hbase, wb.x, d4);  lds_acc2(hbase, wb.y, d5);
        lds_acc2(hbase, wb.z, d6);  lds_acc2(hbase, wb.w, d7);
        lds_acc2(hbase, wc.x, d8);  lds_acc2(hbase, wc.y, d9);
        lds_acc2(hbase, wc.z, d10); lds_acc2(hbase, wc.w, d11);
        lds_acc2(hbase, wd.x, d12); lds_acc2(hbase, wd.y, d13);
        lds_acc2(hbase, wd.z, d14); lds_acc2(hbase, wd.w, d15);
      }
#pragma unroll 1
      for (; j < ecnt; ++j) {
        unsigned int w = lst[j];
        unsigned int d = *(const unsigned int*)&xin[(w >> 4) * 128 + l2];
        lds_acc2(hbase, w, d);
      }
    }
    // convert own rows -> swizzled bf16 sA (wave-private, no barrier needed)
    int ch = lane >> 2;            // logical 8-elem chunk 0..15
    int el = (lane & 3) * 2;       // element within chunk
#pragma unroll 1
    for (int s = 0; s < 16; ++s) {
      int r = wave * 16 + s;
      float2 c = *(float2*)&hF[r * 128 + l2];
      int ph = (ch + r) & 15;
      *(unsigned int*)&sA[(r * 16 + ph) * 8 + el] = pack2(c.x, c.y);
    }
  }
  __syncthreads();   // all hF reads done; sA complete

  // Stage W1 into the hF space (reused as sW).
  unsigned short* sW = (unsigned short*)hF;
  const uint4* gw1 = (const uint4*)W1b;
#pragma unroll
  for (int p = 0; p < 8; ++p) {
    int g = p * 256 + tid;
    int r = g >> 4, b = g & 15;
    int ph = (b + r) & 15;
    *(uint4*)&sW[(r * 16 + ph) * 8] = gw1[g];
  }
  __syncthreads();   // W1 staged

  int l16 = lane & 15;
  int quad = lane >> 4;
  int arow = wave * 16 + l16;

  // ---- GEMM1 ----
  {
    bfrag8 af[4];
#pragma unroll
    for (int k = 0; k < 4; ++k) {
      int ph = (k * 4 + quad + arow) & 15;
      af[k] = *(const bfrag8*)&sA[(arow * 16 + ph) * 8];
    }
    facc4 acc[8];
#pragma unroll
    for (int t = 0; t < 8; ++t) acc[t] = (facc4){0.f, 0.f, 0.f, 0.f};
#pragma unroll
    for (int k = 0; k < 4; ++k) {
#pragma unroll
      for (int t = 0; t < 8; ++t) {
        int r = t * 16 + l16;
        int ph = (k * 4 + quad + r) & 15;
        bfrag8 bf = *(const bfrag8*)&sW[(r * 16 + ph) * 8];
        acc[t] = __builtin_amdgcn_mfma_f32_16x16x32_bf16(af[k], bf, acc[t], 0, 0, 0);
      }
    }
#pragma unroll
    for (int t = 0; t < 8; ++t) {
      int col = t * 16 + l16;
      float b = bias1[col];
      int cb = col >> 3, ce = col & 7;
#pragma unroll
      for (int i = 0; i < 4; ++i) {
        int row = wave * 16 + quad * 4 + i;
        float v = acc[t][i] + b;
        int ph = (cb + row) & 15;
        sA[(row * 16 + ph) * 8 + ce] = f2bf(v > 0.f ? v : 0.f);
      }
    }
  }
  __syncthreads();   // all W1 reads done before restage

  const uint4* gw2 = (const uint4*)W2b;
#pragma unroll
  for (int p = 0; p < 8; ++p) {
    int g = p * 256 + tid;
    int r = g >> 4, b = g & 15;
    int ph = (b + r) & 15;
    *(uint4*)&sW[(r * 16 + ph) * 8] = gw2[g];
  }
  __syncthreads();   // W2 staged before GEMM2 reads

  // ---- GEMM2 ----
  {
    bfrag8 af[4];
#pragma unroll
    for (int k = 0; k < 4; ++k) {
      int ph = (k * 4 + quad + arow) & 15;
      af[k] = *(const bfrag8*)&sA[(arow * 16 + ph) * 8];
    }
    facc4 acc[8];
#pragma unroll
    for (int t = 0; t < 8; ++t) acc[t] = (facc4){0.f, 0.f, 0.f, 0.f};
#pragma unroll
    for (int k = 0; k < 4; ++k) {
#pragma unroll
      for (int t = 0; t < 8; ++t) {
        int r = t * 16 + l16;
        int ph = (k * 4 + quad + r) & 15;
        bfrag8 bf = *(const bfrag8*)&sW[(r * 16 + ph) * 8];
        acc[t] = __builtin_amdgcn_mfma_f32_16x16x32_bf16(af[k], bf, acc[t], 0, 0, 0);
      }
    }
#pragma unroll
    for (int t = 0; t < 8; ++t) {
      int col = t * 16 + l16;
      float b = bias2[col];
      float sc = 1.f, sh = 0.f;
      if (mode == 1) { sc = scale[col]; sh = shift[col]; }
      int cb = col >> 3, ce = col & 7;
#pragma unroll
      for (int i = 0; i < 4; ++i) {
        int row = wave * 16 + quad * 4 + i;
        float v = acc[t][i] + b;
        v = v > 0.f ? v : 0.f;
        if (mode == 1) v = v * sc + sh;
        int ph = (cb + row) & 15;
        sA[(row * 16 + ph) * 8 + ce] = f2bf(v);
      }
    }
  }
  __syncthreads();

  if (doPool) {
    // Last layer: segment-sum this tile's rows by graph id straight out of
    // LDS (batch sorted -> at most a couple of run breaks per 64-row tile).
    if (tid < 128) {
      int fcol = tid;
      int cb = fcol >> 3, ce = fcol & 7;
      float acc = 0.f;
      int cur = -1;
      for (int r = 0; r < 64; ++r) {
        int row = bRow + r;
        if (row >= M) break;
        int b = batch[row];
        if (b != cur) {
          if (cur >= 0) atomicAdd(&pooled[cur * 128 + fcol], acc);
          cur = b;
          acc = 0.f;
        }
        int ph = (cb + r) & 15;
        acc += bf2f(sA[(r * 16 + ph) * 8 + ce]);
      }
      if (cur >= 0) atomicAdd(&pooled[cur * 128 + fcol], acc);
    }
  } else {
#pragma unroll
    for (int p = 0; p < 4; ++p) {
      int g = p * 256 + tid;
      int r = g >> 4, b = g & 15;
      int ph = (b + r) & 15;
      int grow = bRow + r;
      if (grow < M)
        *(uint4*)&Out[grow * 128 + b * 8] = *(const uint4*)&sA[(r * 16 + ph) * 8];
    }
  }
}

// Fused head: h1 = relu(pooled[r]@fc1_W^T+b1) in LDS, then out[r] = h1@fc2_W^T+b2.
__global__ __launch_bounds__(128) void fc_kernel(const float* __restrict__ pooled,
                                                 const float* __restrict__ W1,
                                                 const float* __restrict__ b1,
                                                 const float* __restrict__ W2,
                                                 const float* __restrict__ b2,
                                                 float* __restrict__ out) {
  __shared__ float sh1[128];
  __shared__ float sp[128];
  int r = blockIdx.x;
  int c = threadIdx.x;
  sp[c] = pooled[r * 128 + c];
  __syncthreads();
  float acc = 0.f;
  for (int k = 0; k < 128; ++k) acc += sp[k] * W1[c * 128 + k];
  acc += b1[c];
  sh1[c] = acc > 0.f ? acc : 0.f;
  __syncthreads();
  if (c < NC) {
    float o = 0.f;
    for (int k = 0; k < 128; ++k) o += sh1[k] * W2[c * 128 + k];
    out[r * NC + c] = o + b2[c];
  }
}

extern "C" void kernel_launch(void* const* d_in, const int* in_sizes, int n_in,
                              void* d_out, int out_size, void* d_ws, size_t ws_size,
                              hipStream_t stream) {
  const int* node_ids = (const int*)d_in[0];
  const int* edge_index = (const int*)d_in[1];
  const int* batch = (const int*)d_in[2];
  const float* emb = (const float*)d_in[3];
  const float* in_W1 = (const float*)d_in[4];
  const float* in_b1 = (const float*)d_in[5];
  const float* in_W2 = (const float*)d_in[6];
  const float* in_b2 = (const float*)d_in[7];
  const float* bn_gamma = (const float*)d_in[8];
  const float* bn_beta = (const float*)d_in[9];
  const float* bn_mean = (const float*)d_in[10];
  const float* bn_var = (const float*)d_in[11];
  const float* out_W1 = (const float*)d_in[12];
  const float* out_b1 = (const float*)d_in[13];
  const float* out_W2 = (const float*)d_in[14];
  const float* out_b2 = (const float*)d_in[15];
  const float* fc1_W = (const float*)d_in[16];
  const float* fc1_b = (const float*)d_in[17];
  const float* fc2_W = (const float*)d_in[18];
  const float* fc2_b = (const float*)d_in[19];
  float* out = (float*)d_out;

  char* ws = (char*)d_ws;
  size_t off = 0;
  auto alloc = [&](size_t bytes) {
    char* p = ws + off;
    off = (off + bytes + 255) & ~(size_t)255;
    return p;
  };
  unsigned short* xb = (unsigned short*)alloc((size_t)NN * 128 * 2);
  unsigned short* hb = (unsigned short*)alloc((size_t)NN * 128 * 2);
  unsigned int* elist = (unsigned int*)alloc((size_t)NGRP * GCAP * 4);
  int* cnt2 = (int*)alloc((size_t)NGRP * NCH2 * 4);
  int* curs = (int*)alloc((size_t)NGRP * NCH2 * 4);
  int* gtot = (int*)alloc((size_t)(NGRP + 64) * 4);
  unsigned short* W1b = (unsigned short*)alloc(128 * 128 * 2);
  unsigned short* W2b = (unsigned short*)alloc(128 * 128 * 2);
  unsigned short* oW1b = (unsigned short*)alloc(128 * 128 * 2);
  unsigned short* oW2b = (unsigned short*)alloc(128 * 128 * 2);
  float* bnscale = (float*)alloc(128 * 4);
  float* bnshift = (float*)alloc(128 * 4);
  float* pooled = (float*)alloc(NG * 128 * 4);

  hipMemsetAsync(cnt2, 0, (size_t)NGRP * NCH2 * 4, stream);
  hipMemsetAsync(pooled, 0, (size_t)NG * 128 * 4, stream);

  prep_kernel<<<64, 256, 0, stream>>>(in_W1, in_W2, out_W1, out_W2,
                                      bn_gamma, bn_beta, bn_mean, bn_var,
                                      W1b, W2b, oW1b, oW2b, bnscale, bnshift);
  int echunks = (NE + 255) / 256;
  count_kernel<<<echunks, 256, 0, stream>>>(edge_index, cnt2);
  scan_kernel<<<(NGRP + 255) / 256, 256, 0, stream>>>(cnt2, curs, gtot);
  place_kernel<<<echunks, 256, 0, stream>>>(edge_index, curs, elist);
  embed_kernel<<<(NN * 32 + 255) / 256, 256, 0, stream>>>(node_ids, emb, xb);

  int mlp_blocks = (NN + 63) / 64;
  const unsigned short* cur = xb;
  unsigned short* nxt = hb;
  for (int l = 0; l < 6; ++l) {
    const unsigned short* w1 = (l < 5) ? W1b : oW1b;
    const unsigned short* w2 = (l < 5) ? W2b : oW2b;
    const float* b1 = (l < 5) ? in_b1 : out_b1;
    const float* b2 = (l < 5) ? in_b2 : out_b2;
    int mode2 = (l < 5) ? 1 : 0;
    int doPool = (l == 5) ? 1 : 0;
    gin_layer_kernel<<<mlp_blocks, 256, 0, stream>>>(
        cur, elist, gtot, w1, w2, b1, b2, bnscale, bnshift,
        nxt, batch, pooled, NN, mode2, doPool);
    const unsigned short* t = cur;
    cur = nxt;
    nxt = (unsigned short*)t;
  }

  fc_kernel<<<NG, 128, 0, stream>>>(pooled, fc1_W, fc1_b, fc2_W, fc2_b, out);
}

// Round 7
// 534.632 us; speedup vs baseline: 1.1863x; 1.1863x over previous
//
#include <hip/hip_runtime.h>

#define NN 50000
#define NE 800000
#define NG 128
#define NC 41
#define CAP 64
#define XG 8            // XCD groups for fill partitioning
#define RNG 6250        // NN / XG

typedef __attribute__((ext_vector_type(8))) short bfrag8;
typedef __attribute__((ext_vector_type(4))) float facc4;

__device__ __forceinline__ float bf2f(unsigned short u) {
  union { unsigned int i; float f; } v; v.i = ((unsigned int)u) << 16; return v.f;
}
__device__ __forceinline__ unsigned short f2bf(float f) {
  union { float f; unsigned int i; } v; v.f = f;
  unsigned int x = v.i;
  x += 0x7fffu + ((x >> 16) & 1u);
  return (unsigned short)(x >> 16);
}
__device__ __forceinline__ void acc_u4(const uint4 u, float* a) {
  union { unsigned int i; float f; } c;
  c.i = u.x << 16;          a[0] += c.f;
  c.i = u.x & 0xffff0000u;  a[1] += c.f;
  c.i = u.y << 16;          a[2] += c.f;
  c.i = u.y & 0xffff0000u;  a[3] += c.f;
  c.i = u.z << 16;          a[4] += c.f;
  c.i = u.z & 0xffff0000u;  a[5] += c.f;
  c.i = u.w << 16;          a[6] += c.f;
  c.i = u.w & 0xffff0000u;  a[7] += c.f;
}
__device__ __forceinline__ unsigned int pack2(float lo, float hi) {
  return (unsigned int)f2bf(lo) | ((unsigned int)f2bf(hi) << 16);
}

// Weights -> bf16, BN affine precompute (applied AFTER relu).
__global__ void prep_kernel(const float* __restrict__ W1, const float* __restrict__ W2,
                            const float* __restrict__ oW1, const float* __restrict__ oW2,
                            const float* __restrict__ gamma, const float* __restrict__ beta,
                            const float* __restrict__ mean, const float* __restrict__ var,
                            unsigned short* W1b, unsigned short* W2b,
                            unsigned short* oW1b, unsigned short* oW2b,
                            float* scale, float* shift) {
  int i = blockIdx.x * 256 + threadIdx.x;
  if (i < 128 * 128) {
    W1b[i] = f2bf(W1[i]);
    W2b[i] = f2bf(W2[i]);
    oW1b[i] = f2bf(oW1[i]);
    oW2b[i] = f2bf(oW2[i]);
  }
  if (i < 128) {
    float s = gamma[i] * rsqrtf(var[i] + 1e-5f);
    scale[i] = s;
    shift[i] = beta[i] - mean[i] * s;
  }
}

// x = emb[node_ids], stored bf16. One thread per 4 feats.
__global__ void embed_kernel(const int* __restrict__ node_ids, const float* __restrict__ emb,
                             unsigned short* __restrict__ xb) {
  int idx = blockIdx.x * 256 + threadIdx.x;
  if (idx >= NN * 32) return;
  int node = idx >> 5, f = (idx & 31) * 4;
  const float4 v = *(const float4*)&emb[node_ids[node] * 128 + f];
  ushort4 o;
  o.x = f2bf(v.x); o.y = f2bf(v.y); o.z = f2bf(v.z); o.w = f2bf(v.w);
  *(ushort4*)&xb[node * 128 + f] = o;
}

// XCD-partitioned edge bucketing (r0 form): block b -> group g=b&7, chunk
// s=b>>3; group g commits only dst in [g*RNG,(g+1)*RNG) -> srclist/cnt slices
// stay L2-local per XCD.
__global__ __launch_bounds__(256) void fill_kernel(const int* __restrict__ ei,
                                                   int* __restrict__ cnt,
                                                   unsigned short* __restrict__ srclist) {
  int b = blockIdx.x;
  int g = b & 7;
  int s = b >> 3;
  int e = s * 256 + threadIdx.x;
  if (e >= NE) return;
  int d = ei[NE + e];
  unsigned int lo = g * RNG;
  if ((unsigned int)(d - lo) < (unsigned int)RNG) {
    int src = ei[e];
    int pos = atomicAdd(&cnt[d], 1);
    if (pos < CAP) srclist[d * CAP + pos] = (unsigned short)src;
  }
}

// Fused GIN layer (r7 = r3 structure + W2 register-prefetch):
//  - Gather model (r1/r2/r3/r6-validated): per-CU MSHR(~16) x latency bound;
//    structure kept exactly as the 485us-verified r3 version.
//  - NEW: W2 is prefetched into 8 uint4 REGISTERS alongside the W1 staging,
//    before the gather -- its L2 latency hides under the MSHR-bound gather
//    phase (idle BW + issue slots there). The mid-MLP W2 restage becomes
//    barrier -> 8 ds_write_b128 -> barrier with NO global loads, removing the
//    only serial L2 burst on the MLP critical path (~50MB/layer chip-wide
//    previously issued post-barrier with nothing to overlap).
//  - LDS stays 48KB -> 3 blocks/CU; +32 VGPR is free (LDS-bound occupancy).
__global__ __launch_bounds__(256) void gin_layer_kernel(
    const unsigned short* __restrict__ xin,
    const int* __restrict__ cnt,
    const unsigned short* __restrict__ srclist,
    const unsigned short* __restrict__ W1b,
    const unsigned short* __restrict__ W2b,
    const float* __restrict__ bias1,
    const float* __restrict__ bias2,
    const float* __restrict__ scale,
    const float* __restrict__ shift,
    unsigned short* __restrict__ Out,
    const int* __restrict__ batch,
    float* __restrict__ pooled,
    int M, int mode, int doPool) {
  __shared__ unsigned short sW[128 * 128];   // 32KB: W1, then W2 (from regs)
  __shared__ unsigned short sA[64 * 128];    // 16KB
  int tid = threadIdx.x;
  int bRow = blockIdx.x * 64;

  // Stage W1 into LDS and W2 into registers: all global loads issued early so
  // they overlap gather latency.
  const uint4* gw1 = (const uint4*)W1b;
  const uint4* gw2 = (const uint4*)W2b;
  uint4 w2r[8];
#pragma unroll
  for (int p = 0; p < 8; ++p) {
    int g = p * 256 + tid;
    int r = g >> 4, b = g & 15;
    int ph = (b + r) & 15;
    *(uint4*)&sW[(r * 16 + ph) * 8] = gw1[g];
  }
#pragma unroll
  for (int p = 0; p < 8; ++p) w2r[p] = gw2[p * 256 + tid];

  // ---- Pipelined aggregation: 16 lanes/node, 4 nodes/wave, 4 passes ----
  {
    int al16 = tid & 15;
    int sub = tid >> 4;          // 0..15
    int f = al16 * 8;

    // Hoist the 4 per-node degree loads (independent, issued together).
    int n0 = bRow + sub, n1 = n0 + 16, n2 = n0 + 32, n3 = n0 + 48;
    int d0 = (n0 < M) ? cnt[n0] : 0;
    int d1 = (n1 < M) ? cnt[n1] : 0;
    int d2 = (n2 < M) ? cnt[n2] : 0;
    int d3 = (n3 < M) ? cnt[n3] : 0;

#pragma unroll 1
    for (int g = 0; g < 4; ++g) {
      int r = g * 16 + sub;      // tile row 0..63
      int node = bRow + r;
      float a[8];
      a[0]=0.f; a[1]=0.f; a[2]=0.f; a[3]=0.f;
      a[4]=0.f; a[5]=0.f; a[6]=0.f; a[7]=0.f;
      if (node < M) {
        int deg = (g == 0) ? d0 : (g == 1) ? d1 : (g == 2) ? d2 : d3;
        if (deg > CAP) deg = CAP;
        const unsigned short* lst = &srclist[node * CAP];
        // self row (issued first, accumulated first)
        acc_u4(*(const uint4*)&xin[node * 128 + f], a);
        int j = 0;
        // main: 16-deep window, both index vectors issued up front
#pragma unroll 1
        for (; j + 16 <= deg; j += 16) {
          uint4 iv0 = *(const uint4*)&lst[j];
          uint4 iv1 = *(const uint4*)&lst[j + 8];
          int p0 = iv0.x & 0xffff, p1 = iv0.x >> 16;
          int p2 = iv0.y & 0xffff, p3 = iv0.y >> 16;
          int p4 = iv0.z & 0xffff, p5 = iv0.z >> 16;
          int p6 = iv0.w & 0xffff, p7 = iv0.w >> 16;
          uint4 uA0 = *(const uint4*)&xin[p0 * 128 + f];
          uint4 uA1 = *(const uint4*)&xin[p1 * 128 + f];
          uint4 uA2 = *(const uint4*)&xin[p2 * 128 + f];
          uint4 uA3 = *(const uint4*)&xin[p3 * 128 + f];
          uint4 uA4 = *(const uint4*)&xin[p4 * 128 + f];
          uint4 uA5 = *(const uint4*)&xin[p5 * 128 + f];
          uint4 uA6 = *(const uint4*)&xin[p6 * 128 + f];
          uint4 uA7 = *(const uint4*)&xin[p7 * 128 + f];
          int q0 = iv1.x & 0xffff, q1 = iv1.x >> 16;
          int q2 = iv1.y & 0xffff, q3 = iv1.y >> 16;
          int q4 = iv1.z & 0xffff, q5 = iv1.z >> 16;
          int q6 = iv1.w & 0xffff, q7 = iv1.w >> 16;
          uint4 uB0 = *(const uint4*)&xin[q0 * 128 + f];
          uint4 uB1 = *(const uint4*)&xin[q1 * 128 + f];
          uint4 uB2 = *(const uint4*)&xin[q2 * 128 + f];
          uint4 uB3 = *(const uint4*)&xin[q3 * 128 + f];
          uint4 uB4 = *(const uint4*)&xin[q4 * 128 + f];
          uint4 uB5 = *(const uint4*)&xin[q5 * 128 + f];
          uint4 uB6 = *(const uint4*)&xin[q6 * 128 + f];
          uint4 uB7 = *(const uint4*)&xin[q7 * 128 + f];
          acc_u4(uA0, a); acc_u4(uA1, a); acc_u4(uA2, a); acc_u4(uA3, a);
          acc_u4(uA4, a); acc_u4(uA5, a); acc_u4(uA6, a); acc_u4(uA7, a);
          acc_u4(uB0, a); acc_u4(uB1, a); acc_u4(uB2, a); acc_u4(uB3, a);
          acc_u4(uB4, a); acc_u4(uB5, a); acc_u4(uB6, a); acc_u4(uB7, a);
        }
        if (j + 8 <= deg) {
          uint4 iv = *(const uint4*)&lst[j];
          int p0 = iv.x & 0xffff, p1 = iv.x >> 16;
          int p2 = iv.y & 0xffff, p3 = iv.y >> 16;
          int p4 = iv.z & 0xffff, p5 = iv.z >> 16;
          int p6 = iv.w & 0xffff, p7 = iv.w >> 16;
          uint4 u0 = *(const uint4*)&xin[p0 * 128 + f];
          uint4 u1 = *(const uint4*)&xin[p1 * 128 + f];
          uint4 u2 = *(const uint4*)&xin[p2 * 128 + f];
          uint4 u3 = *(const uint4*)&xin[p3 * 128 + f];
          uint4 u4 = *(const uint4*)&xin[p4 * 128 + f];
          uint4 u5 = *(const uint4*)&xin[p5 * 128 + f];
          uint4 u6 = *(const uint4*)&xin[p6 * 128 + f];
          uint4 u7 = *(const uint4*)&xin[p7 * 128 + f];
          acc_u4(u0, a); acc_u4(u1, a); acc_u4(u2, a); acc_u4(u3, a);
          acc_u4(u4, a); acc_u4(u5, a); acc_u4(u6, a); acc_u4(u7, a);
          j += 8;
        }
        if (j + 4 <= deg) {
          uint2 iv = *(const uint2*)&lst[j];
          int p0 = iv.x & 0xffff, p1 = iv.x >> 16;
          int p2 = iv.y & 0xffff, p3 = iv.y >> 16;
          uint4 u0 = *(const uint4*)&xin[p0 * 128 + f];
          uint4 u1 = *(const uint4*)&xin[p1 * 128 + f];
          uint4 u2 = *(const uint4*)&xin[p2 * 128 + f];
          uint4 u3 = *(const uint4*)&xin[p3 * 128 + f];
          acc_u4(u0, a); acc_u4(u1, a); acc_u4(u2, a); acc_u4(u3, a);
          j += 4;
        }
        for (; j < deg; ++j) {
          uint4 u = *(const uint4*)&xin[(int)lst[j] * 128 + f];
          acc_u4(u, a);
        }
      }
      int ph = (al16 + r) & 15;
      uint4 o;
      o.x = pack2(a[0], a[1]); o.y = pack2(a[2], a[3]);
      o.z = pack2(a[4], a[5]); o.w = pack2(a[6], a[7]);
      *(uint4*)&sA[(r * 16 + ph) * 8] = o;
    }
  }
  __syncthreads();

  int wave = tid >> 6;
  int lane = tid & 63;
  int l16 = lane & 15;
  int quad = lane >> 4;
  int arow = wave * 16 + l16;

  // ---- GEMM1 ----
  {
    bfrag8 af[4];
#pragma unroll
    for (int k = 0; k < 4; ++k) {
      int ph = (k * 4 + quad + arow) & 15;
      af[k] = *(const bfrag8*)&sA[(arow * 16 + ph) * 8];
    }
    facc4 acc[8];
#pragma unroll
    for (int t = 0; t < 8; ++t) acc[t] = (facc4){0.f, 0.f, 0.f, 0.f};
#pragma unroll
    for (int k = 0; k < 4; ++k) {
#pragma unroll
      for (int t = 0; t < 8; ++t) {
        int r = t * 16 + l16;
        int ph = (k * 4 + quad + r) & 15;
        bfrag8 bf = *(const bfrag8*)&sW[(r * 16 + ph) * 8];
        acc[t] = __builtin_amdgcn_mfma_f32_16x16x32_bf16(af[k], bf, acc[t], 0, 0, 0);
      }
    }
#pragma unroll
    for (int t = 0; t < 8; ++t) {
      int col = t * 16 + l16;
      float b = bias1[col];
      int cb = col >> 3, ce = col & 7;
#pragma unroll
      for (int i = 0; i < 4; ++i) {
        int row = wave * 16 + quad * 4 + i;
        float v = acc[t][i] + b;
        int ph = (cb + row) & 15;
        sA[(row * 16 + ph) * 8 + ce] = f2bf(v > 0.f ? v : 0.f);
      }
    }
  }
  __syncthreads();   // all W1 reads done before overwrite

  // W2: registers -> LDS (no global access in this critical section)
#pragma unroll
  for (int p = 0; p < 8; ++p) {
    int g = p * 256 + tid;
    int r = g >> 4, b = g & 15;
    int ph = (b + r) & 15;
    *(uint4*)&sW[(r * 16 + ph) * 8] = w2r[p];
  }
  __syncthreads();   // W2 staged before GEMM2 reads

  // ---- GEMM2 ----
  {
    bfrag8 af[4];
#pragma unroll
    for (int k = 0; k < 4; ++k) {
      int ph = (k * 4 + quad + arow) & 15;
      af[k] = *(const bfrag8*)&sA[(arow * 16 + ph) * 8];
    }
    facc4 acc[8];
#pragma unroll
    for (int t = 0; t < 8; ++t) acc[t] = (facc4){0.f, 0.f, 0.f, 0.f};
#pragma unroll
    for (int k = 0; k < 4; ++k) {
#pragma unroll
      for (int t = 0; t < 8; ++t) {
        int r = t * 16 + l16;
        int ph = (k * 4 + quad + r) & 15;
        bfrag8 bf = *(const bfrag8*)&sW[(r * 16 + ph) * 8];
        acc[t] = __builtin_amdgcn_mfma_f32_16x16x32_bf16(af[k], bf, acc[t], 0, 0, 0);
      }
    }
#pragma unroll
    for (int t = 0; t < 8; ++t) {
      int col = t * 16 + l16;
      float b = bias2[col];
      float sc = 1.f, sh = 0.f;
      if (mode == 1) { sc = scale[col]; sh = shift[col]; }
      int cb = col >> 3, ce = col & 7;
#pragma unroll
      for (int i = 0; i < 4; ++i) {
        int row = wave * 16 + quad * 4 + i;
        float v = acc[t][i] + b;
        v = v > 0.f ? v : 0.f;
        if (mode == 1) v = v * sc + sh;
        int ph = (cb + row) & 15;
        sA[(row * 16 + ph) * 8 + ce] = f2bf(v);
      }
    }
  }
  __syncthreads();

  if (doPool) {
    // Last layer: segment-sum this tile's rows by graph id straight out of
    // LDS (batch sorted -> at most a couple of run breaks per 64-row tile).
    if (tid < 128) {
      int fcol = tid;
      int cb = fcol >> 3, ce = fcol & 7;
      float acc = 0.f;
      int cur = -1;
      for (int r = 0; r < 64; ++r) {
        int row = bRow + r;
        if (row >= M) break;
        int b = batch[row];
        if (b != cur) {
          if (cur >= 0) atomicAdd(&pooled[cur * 128 + fcol], acc);
          cur = b;
          acc = 0.f;
        }
        int ph = (cb + r) & 15;
        acc += bf2f(sA[(r * 16 + ph) * 8 + ce]);
      }
      if (cur >= 0) atomicAdd(&pooled[cur * 128 + fcol], acc);
    }
  } else {
#pragma unroll
    for (int p = 0; p < 4; ++p) {
      int g = p * 256 + tid;
      int r = g >> 4, b = g & 15;
      int ph = (b + r) & 15;
      int grow = bRow + r;
      if (grow < M)
        *(uint4*)&Out[grow * 128 + b * 8] = *(const uint4*)&sA[(r * 16 + ph) * 8];
    }
  }
}

// Fused head: h1 = relu(pooled[r]@fc1_W^T+b1) in LDS, then out[r] = h1@fc2_W^T+b2.
__global__ __launch_bounds__(128) void fc_kernel(const float* __restrict__ pooled,
                                                 const float* __restrict__ W1,
                                                 const float* __restrict__ b1,
                                                 const float* __restrict__ W2,
                                                 const float* __restrict__ b2,
                                                 float* __restrict__ out) {
  __shared__ float sh1[128];
  __shared__ float sp[128];
  int r = blockIdx.x;
  int c = threadIdx.x;
  sp[c] = pooled[r * 128 + c];
  __syncthreads();
  float acc = 0.f;
  for (int k = 0; k < 128; ++k) acc += sp[k] * W1[c * 128 + k];
  acc += b1[c];
  sh1[c] = acc > 0.f ? acc : 0.f;
  __syncthreads();
  if (c < NC) {
    float o = 0.f;
    for (int k = 0; k < 128; ++k) o += sh1[k] * W2[c * 128 + k];
    out[r * NC + c] = o + b2[c];
  }
}

extern "C" void kernel_launch(void* const* d_in, const int* in_sizes, int n_in,
                              void* d_out, int out_size, void* d_ws, size_t ws_size,
                              hipStream_t stream) {
  const int* node_ids = (const int*)d_in[0];
  const int* edge_index = (const int*)d_in[1];
  const int* batch = (const int*)d_in[2];
  const float* emb = (const float*)d_in[3];
  const float* in_W1 = (const float*)d_in[4];
  const float* in_b1 = (const float*)d_in[5];
  const float* in_W2 = (const float*)d_in[6];
  const float* in_b2 = (const float*)d_in[7];
  const float* bn_gamma = (const float*)d_in[8];
  const float* bn_beta = (const float*)d_in[9];
  const float* bn_mean = (const float*)d_in[10];
  const float* bn_var = (const float*)d_in[11];
  const float* out_W1 = (const float*)d_in[12];
  const float* out_b1 = (const float*)d_in[13];
  const float* out_W2 = (const float*)d_in[14];
  const float* out_b2 = (const float*)d_in[15];
  const float* fc1_W = (const float*)d_in[16];
  const float* fc1_b = (const float*)d_in[17];
  const float* fc2_W = (const float*)d_in[18];
  const float* fc2_b = (const float*)d_in[19];
  float* out = (float*)d_out;

  char* ws = (char*)d_ws;
  size_t off = 0;
  auto alloc = [&](size_t bytes) {
    char* p = ws + off;
    off = (off + bytes + 255) & ~(size_t)255;
    return p;
  };
  unsigned short* xb = (unsigned short*)alloc((size_t)NN * 128 * 2);
  unsigned short* hb = (unsigned short*)alloc((size_t)NN * 128 * 2);
  unsigned short* srclist = (unsigned short*)alloc((size_t)NN * CAP * 2);
  int* cnt = (int*)alloc((size_t)NN * 4);
  unsigned short* W1b = (unsigned short*)alloc(128 * 128 * 2);
  unsigned short* W2b = (unsigned short*)alloc(128 * 128 * 2);
  unsigned short* oW1b = (unsigned short*)alloc(128 * 128 * 2);
  unsigned short* oW2b = (unsigned short*)alloc(128 * 128 * 2);
  float* bnscale = (float*)alloc(128 * 4);
  float* bnshift = (float*)alloc(128 * 4);
  float* pooled = (float*)alloc(NG * 128 * 4);

  hipMemsetAsync(cnt, 0, (size_t)NN * 4, stream);
  hipMemsetAsync(pooled, 0, (size_t)NG * 128 * 4, stream);

  prep_kernel<<<64, 256, 0, stream>>>(in_W1, in_W2, out_W1, out_W2,
                                      bn_gamma, bn_beta, bn_mean, bn_var,
                                      W1b, W2b, oW1b, oW2b, bnscale, bnshift);
  int chunks = (NE + 255) / 256;
  fill_kernel<<<chunks * XG, 256, 0, stream>>>(edge_index, cnt, srclist);
  embed_kernel<<<(NN * 32 + 255) / 256, 256, 0, stream>>>(node_ids, emb, xb);

  int mlp_blocks = (NN + 63) / 64;
  const unsigned short* cur = xb;
  unsigned short* nxt = hb;
  for (int l = 0; l < 6; ++l) {
    const unsigned short* w1 = (l < 5) ? W1b : oW1b;
    const unsigned short* w2 = (l < 5) ? W2b : oW2b;
    const float* b1 = (l < 5) ? in_b1 : out_b1;
    const float* b2 = (l < 5) ? in_b2 : out_b2;
    int mode2 = (l < 5) ? 1 : 0;
    int doPool = (l == 5) ? 1 : 0;
    gin_layer_kernel<<<mlp_blocks, 256, 0, stream>>>(
        cur, cnt, srclist, w1, w2, b1, b2, bnscale, bnshift,
        nxt, batch, pooled, NN, mode2, doPool);
    const unsigned short* t = cur;
    cur = nxt;
    nxt = (unsigned short*)t;
  }

  fc_kernel<<<NG, 128, 0, stream>>>(pooled, fc1_W, fc1_b, fc2_W, fc2_b, out);
}

// Round 8
// 531.082 us; speedup vs baseline: 1.1943x; 1.0067x over previous
//
#include <hip/hip_runtime.h>

#define NN 50000
#define NE 800000
#define NG 128
#define NC 41
#define CAP 64
#define XG 8            // XCD groups for fill partitioning
#define RNG 6250        // NN / XG

typedef __attribute__((ext_vector_type(8))) short bfrag8;
typedef __attribute__((ext_vector_type(4))) float facc4;

__device__ __forceinline__ float bf2f(unsigned short u) {
  union { unsigned int i; float f; } v; v.i = ((unsigned int)u) << 16; return v.f;
}
__device__ __forceinline__ unsigned short f2bf(float f) {
  union { float f; unsigned int i; } v; v.f = f;
  unsigned int x = v.i;
  x += 0x7fffu + ((x >> 16) & 1u);
  return (unsigned short)(x >> 16);
}
__device__ __forceinline__ void acc_u4(const uint4 u, float* a) {
  union { unsigned int i; float f; } c;
  c.i = u.x << 16;          a[0] += c.f;
  c.i = u.x & 0xffff0000u;  a[1] += c.f;
  c.i = u.y << 16;          a[2] += c.f;
  c.i = u.y & 0xffff0000u;  a[3] += c.f;
  c.i = u.z << 16;          a[4] += c.f;
  c.i = u.z & 0xffff0000u;  a[5] += c.f;
  c.i = u.w << 16;          a[6] += c.f;
  c.i = u.w & 0xffff0000u;  a[7] += c.f;
}
__device__ __forceinline__ unsigned int pack2(float lo, float hi) {
  return (unsigned int)f2bf(lo) | ((unsigned int)f2bf(hi) << 16);
}

// Weights -> bf16, BN affine precompute (applied AFTER relu).
__global__ void prep_kernel(const float* __restrict__ W1, const float* __restrict__ W2,
                            const float* __restrict__ oW1, const float* __restrict__ oW2,
                            const float* __restrict__ gamma, const float* __restrict__ beta,
                            const float* __restrict__ mean, const float* __restrict__ var,
                            unsigned short* W1b, unsigned short* W2b,
                            unsigned short* oW1b, unsigned short* oW2b,
                            float* scale, float* shift) {
  int i = blockIdx.x * 256 + threadIdx.x;
  if (i < 128 * 128) {
    W1b[i] = f2bf(W1[i]);
    W2b[i] = f2bf(W2[i]);
    oW1b[i] = f2bf(oW1[i]);
    oW2b[i] = f2bf(oW2[i]);
  }
  if (i < 128) {
    float s = gamma[i] * rsqrtf(var[i] + 1e-5f);
    scale[i] = s;
    shift[i] = beta[i] - mean[i] * s;
  }
}

// x = emb[node_ids], stored bf16. One thread per 4 feats.
__global__ void embed_kernel(const int* __restrict__ node_ids, const float* __restrict__ emb,
                             unsigned short* __restrict__ xb) {
  int idx = blockIdx.x * 256 + threadIdx.x;
  if (idx >= NN * 32) return;
  int node = idx >> 5, f = (idx & 31) * 4;
  const float4 v = *(const float4*)&emb[node_ids[node] * 128 + f];
  ushort4 o;
  o.x = f2bf(v.x); o.y = f2bf(v.y); o.z = f2bf(v.z); o.w = f2bf(v.w);
  *(ushort4*)&xb[node * 128 + f] = o;
}

// XCD-partitioned edge bucketing (r0 form): block b -> group g=b&7, chunk
// s=b>>3; group g commits only dst in [g*RNG,(g+1)*RNG) -> srclist/cnt slices
// stay L2-local per XCD.
__global__ __launch_bounds__(256) void fill_kernel(const int* __restrict__ ei,
                                                   int* __restrict__ cnt,
                                                   unsigned short* __restrict__ srclist) {
  int b = blockIdx.x;
  int g = b & 7;
  int s = b >> 3;
  int e = s * 256 + threadIdx.x;
  if (e >= NE) return;
  int d = ei[NE + e];
  unsigned int lo = g * RNG;
  if ((unsigned int)(d - lo) < (unsigned int)RNG) {
    int src = ei[e];
    int pos = atomicAdd(&cnt[d], 1);
    if (pos < CAP) srclist[d * CAP + pos] = (unsigned short)src;
  }
}

// Fused GIN layer (r8 = r7 + __launch_bounds__(256,3)):
//  - r7's W2 register-prefetch SPILLED to scratch (WRITE_SIZE 453KB->25.5MB
//    = 782*256*128B exactly; VGPR stuck at 88): plain launch_bounds(256) let
//    the allocator target high occupancy we can't reach anyway (LDS caps us
//    at 3 blocks/CU = 3 waves/EU). Declaring min-waves=3 raises the VGPR
//    budget to ~170 so w2r stays register-resident.
//  - Structure otherwise identical to the 485us-verified r3 + W2-prefetch:
//    all global W loads issued before the gather (latency hidden under the
//    MSHR-bound gather), mid-MLP restage = regs -> 8x ds_write_b128 only.
__global__ __launch_bounds__(256, 3) void gin_layer_kernel(
    const unsigned short* __restrict__ xin,
    const int* __restrict__ cnt,
    const unsigned short* __restrict__ srclist,
    const unsigned short* __restrict__ W1b,
    const unsigned short* __restrict__ W2b,
    const float* __restrict__ bias1,
    const float* __restrict__ bias2,
    const float* __restrict__ scale,
    const float* __restrict__ shift,
    unsigned short* __restrict__ Out,
    const int* __restrict__ batch,
    float* __restrict__ pooled,
    int M, int mode, int doPool) {
  __shared__ unsigned short sW[128 * 128];   // 32KB: W1, then W2 (from regs)
  __shared__ unsigned short sA[64 * 128];    // 16KB
  int tid = threadIdx.x;
  int bRow = blockIdx.x * 64;

  // Stage W1 into LDS and W2 into registers: all global loads issued early so
  // they overlap gather latency.
  const uint4* gw1 = (const uint4*)W1b;
  const uint4* gw2 = (const uint4*)W2b;
  uint4 w2r[8];
#pragma unroll
  for (int p = 0; p < 8; ++p) {
    int g = p * 256 + tid;
    int r = g >> 4, b = g & 15;
    int ph = (b + r) & 15;
    *(uint4*)&sW[(r * 16 + ph) * 8] = gw1[g];
  }
#pragma unroll
  for (int p = 0; p < 8; ++p) w2r[p] = gw2[p * 256 + tid];

  // ---- Pipelined aggregation: 16 lanes/node, 4 nodes/wave, 4 passes ----
  {
    int al16 = tid & 15;
    int sub = tid >> 4;          // 0..15
    int f = al16 * 8;

    // Hoist the 4 per-node degree loads (independent, issued together).
    int n0 = bRow + sub, n1 = n0 + 16, n2 = n0 + 32, n3 = n0 + 48;
    int d0 = (n0 < M) ? cnt[n0] : 0;
    int d1 = (n1 < M) ? cnt[n1] : 0;
    int d2 = (n2 < M) ? cnt[n2] : 0;
    int d3 = (n3 < M) ? cnt[n3] : 0;

#pragma unroll 1
    for (int g = 0; g < 4; ++g) {
      int r = g * 16 + sub;      // tile row 0..63
      int node = bRow + r;
      float a[8];
      a[0]=0.f; a[1]=0.f; a[2]=0.f; a[3]=0.f;
      a[4]=0.f; a[5]=0.f; a[6]=0.f; a[7]=0.f;
      if (node < M) {
        int deg = (g == 0) ? d0 : (g == 1) ? d1 : (g == 2) ? d2 : d3;
        if (deg > CAP) deg = CAP;
        const unsigned short* lst = &srclist[node * CAP];
        // self row (issued first, accumulated first)
        acc_u4(*(const uint4*)&xin[node * 128 + f], a);
        int j = 0;
        // main: 16-deep window, both index vectors issued up front
#pragma unroll 1
        for (; j + 16 <= deg; j += 16) {
          uint4 iv0 = *(const uint4*)&lst[j];
          uint4 iv1 = *(const uint4*)&lst[j + 8];
          int p0 = iv0.x & 0xffff, p1 = iv0.x >> 16;
          int p2 = iv0.y & 0xffff, p3 = iv0.y >> 16;
          int p4 = iv0.z & 0xffff, p5 = iv0.z >> 16;
          int p6 = iv0.w & 0xffff, p7 = iv0.w >> 16;
          uint4 uA0 = *(const uint4*)&xin[p0 * 128 + f];
          uint4 uA1 = *(const uint4*)&xin[p1 * 128 + f];
          uint4 uA2 = *(const uint4*)&xin[p2 * 128 + f];
          uint4 uA3 = *(const uint4*)&xin[p3 * 128 + f];
          uint4 uA4 = *(const uint4*)&xin[p4 * 128 + f];
          uint4 uA5 = *(const uint4*)&xin[p5 * 128 + f];
          uint4 uA6 = *(const uint4*)&xin[p6 * 128 + f];
          uint4 uA7 = *(const uint4*)&xin[p7 * 128 + f];
          int q0 = iv1.x & 0xffff, q1 = iv1.x >> 16;
          int q2 = iv1.y & 0xffff, q3 = iv1.y >> 16;
          int q4 = iv1.z & 0xffff, q5 = iv1.z >> 16;
          int q6 = iv1.w & 0xffff, q7 = iv1.w >> 16;
          uint4 uB0 = *(const uint4*)&xin[q0 * 128 + f];
          uint4 uB1 = *(const uint4*)&xin[q1 * 128 + f];
          uint4 uB2 = *(const uint4*)&xin[q2 * 128 + f];
          uint4 uB3 = *(const uint4*)&xin[q3 * 128 + f];
          uint4 uB4 = *(const uint4*)&xin[q4 * 128 + f];
          uint4 uB5 = *(const uint4*)&xin[q5 * 128 + f];
          uint4 uB6 = *(const uint4*)&xin[q6 * 128 + f];
          uint4 uB7 = *(const uint4*)&xin[q7 * 128 + f];
          acc_u4(uA0, a); acc_u4(uA1, a); acc_u4(uA2, a); acc_u4(uA3, a);
          acc_u4(uA4, a); acc_u4(uA5, a); acc_u4(uA6, a); acc_u4(uA7, a);
          acc_u4(uB0, a); acc_u4(uB1, a); acc_u4(uB2, a); acc_u4(uB3, a);
          acc_u4(uB4, a); acc_u4(uB5, a); acc_u4(uB6, a); acc_u4(uB7, a);
        }
        if (j + 8 <= deg) {
          uint4 iv = *(const uint4*)&lst[j];
          int p0 = iv.x & 0xffff, p1 = iv.x >> 16;
          int p2 = iv.y & 0xffff, p3 = iv.y >> 16;
          int p4 = iv.z & 0xffff, p5 = iv.z >> 16;
          int p6 = iv.w & 0xffff, p7 = iv.w >> 16;
          uint4 u0 = *(const uint4*)&xin[p0 * 128 + f];
          uint4 u1 = *(const uint4*)&xin[p1 * 128 + f];
          uint4 u2 = *(const uint4*)&xin[p2 * 128 + f];
          uint4 u3 = *(const uint4*)&xin[p3 * 128 + f];
          uint4 u4 = *(const uint4*)&xin[p4 * 128 + f];
          uint4 u5 = *(const uint4*)&xin[p5 * 128 + f];
          uint4 u6 = *(const uint4*)&xin[p6 * 128 + f];
          uint4 u7 = *(const uint4*)&xin[p7 * 128 + f];
          acc_u4(u0, a); acc_u4(u1, a); acc_u4(u2, a); acc_u4(u3, a);
          acc_u4(u4, a); acc_u4(u5, a); acc_u4(u6, a); acc_u4(u7, a);
          j += 8;
        }
        if (j + 4 <= deg) {
          uint2 iv = *(const uint2*)&lst[j];
          int p0 = iv.x & 0xffff, p1 = iv.x >> 16;
          int p2 = iv.y & 0xffff, p3 = iv.y >> 16;
          uint4 u0 = *(const uint4*)&xin[p0 * 128 + f];
          uint4 u1 = *(const uint4*)&xin[p1 * 128 + f];
          uint4 u2 = *(const uint4*)&xin[p2 * 128 + f];
          uint4 u3 = *(const uint4*)&xin[p3 * 128 + f];
          acc_u4(u0, a); acc_u4(u1, a); acc_u4(u2, a); acc_u4(u3, a);
          j += 4;
        }
        for (; j < deg; ++j) {
          uint4 u = *(const uint4*)&xin[(int)lst[j] * 128 + f];
          acc_u4(u, a);
        }
      }
      int ph = (al16 + r) & 15;
      uint4 o;
      o.x = pack2(a[0], a[1]); o.y = pack2(a[2], a[3]);
      o.z = pack2(a[4], a[5]); o.w = pack2(a[6], a[7]);
      *(uint4*)&sA[(r * 16 + ph) * 8] = o;
    }
  }
  __syncthreads();

  int wave = tid >> 6;
  int lane = tid & 63;
  int l16 = lane & 15;
  int quad = lane >> 4;
  int arow = wave * 16 + l16;

  // ---- GEMM1 ----
  {
    bfrag8 af[4];
#pragma unroll
    for (int k = 0; k < 4; ++k) {
      int ph = (k * 4 + quad + arow) & 15;
      af[k] = *(const bfrag8*)&sA[(arow * 16 + ph) * 8];
    }
    facc4 acc[8];
#pragma unroll
    for (int t = 0; t < 8; ++t) acc[t] = (facc4){0.f, 0.f, 0.f, 0.f};
#pragma unroll
    for (int k = 0; k < 4; ++k) {
#pragma unroll
      for (int t = 0; t < 8; ++t) {
        int r = t * 16 + l16;
        int ph = (k * 4 + quad + r) & 15;
        bfrag8 bf = *(const bfrag8*)&sW[(r * 16 + ph) * 8];
        acc[t] = __builtin_amdgcn_mfma_f32_16x16x32_bf16(af[k], bf, acc[t], 0, 0, 0);
      }
    }
#pragma unroll
    for (int t = 0; t < 8; ++t) {
      int col = t * 16 + l16;
      float b = bias1[col];
      int cb = col >> 3, ce = col & 7;
#pragma unroll
      for (int i = 0; i < 4; ++i) {
        int row = wave * 16 + quad * 4 + i;
        float v = acc[t][i] + b;
        int ph = (cb + row) & 15;
        sA[(row * 16 + ph) * 8 + ce] = f2bf(v > 0.f ? v : 0.f);
      }
    }
  }
  __syncthreads();   // all W1 reads done before overwrite

  // W2: registers -> LDS (no global access in this critical section)
#pragma unroll
  for (int p = 0; p < 8; ++p) {
    int g = p * 256 + tid;
    int r = g >> 4, b = g & 15;
    int ph = (b + r) & 15;
    *(uint4*)&sW[(r * 16 + ph) * 8] = w2r[p];
  }
  __syncthreads();   // W2 staged before GEMM2 reads

  // ---- GEMM2 ----
  {
    bfrag8 af[4];
#pragma unroll
    for (int k = 0; k < 4; ++k) {
      int ph = (k * 4 + quad + arow) & 15;
      af[k] = *(const bfrag8*)&sA[(arow * 16 + ph) * 8];
    }
    facc4 acc[8];
#pragma unroll
    for (int t = 0; t < 8; ++t) acc[t] = (facc4){0.f, 0.f, 0.f, 0.f};
#pragma unroll
    for (int k = 0; k < 4; ++k) {
#pragma unroll
      for (int t = 0; t < 8; ++t) {
        int r = t * 16 + l16;
        int ph = (k * 4 + quad + r) & 15;
        bfrag8 bf = *(const bfrag8*)&sW[(r * 16 + ph) * 8];
        acc[t] = __builtin_amdgcn_mfma_f32_16x16x32_bf16(af[k], bf, acc[t], 0, 0, 0);
      }
    }
#pragma unroll
    for (int t = 0; t < 8; ++t) {
      int col = t * 16 + l16;
      float b = bias2[col];
      float sc = 1.f, sh = 0.f;
      if (mode == 1) { sc = scale[col]; sh = shift[col]; }
      int cb = col >> 3, ce = col & 7;
#pragma unroll
      for (int i = 0; i < 4; ++i) {
        int row = wave * 16 + quad * 4 + i;
        float v = acc[t][i] + b;
        v = v > 0.f ? v : 0.f;
        if (mode == 1) v = v * sc + sh;
        int ph = (cb + row) & 15;
        sA[(row * 16 + ph) * 8 + ce] = f2bf(v);
      }
    }
  }
  __syncthreads();

  if (doPool) {
    // Last layer: segment-sum this tile's rows by graph id straight out of
    // LDS (batch sorted -> at most a couple of run breaks per 64-row tile).
    if (tid < 128) {
      int fcol = tid;
      int cb = fcol >> 3, ce = fcol & 7;
      float acc = 0.f;
      int cur = -1;
      for (int r = 0; r < 64; ++r) {
        int row = bRow + r;
        if (row >= M) break;
        int b = batch[row];
        if (b != cur) {
          if (cur >= 0) atomicAdd(&pooled[cur * 128 + fcol], acc);
          cur = b;
          acc = 0.f;
        }
        int ph = (cb + r) & 15;
        acc += bf2f(sA[(r * 16 + ph) * 8 + ce]);
      }
      if (cur >= 0) atomicAdd(&pooled[cur * 128 + fcol], acc);
    }
  } else {
#pragma unroll
    for (int p = 0; p < 4; ++p) {
      int g = p * 256 + tid;
      int r = g >> 4, b = g & 15;
      int ph = (b + r) & 15;
      int grow = bRow + r;
      if (grow < M)
        *(uint4*)&Out[grow * 128 + b * 8] = *(const uint4*)&sA[(r * 16 + ph) * 8];
    }
  }
}

// Fused head: h1 = relu(pooled[r]@fc1_W^T+b1) in LDS, then out[r] = h1@fc2_W^T+b2.
__global__ __launch_bounds__(128) void fc_kernel(const float* __restrict__ pooled,
                                                 const float* __restrict__ W1,
                                                 const float* __restrict__ b1,
                                                 const float* __restrict__ W2,
                                                 const float* __restrict__ b2,
                                                 float* __restrict__ out) {
  __shared__ float sh1[128];
  __shared__ float sp[128];
  int r = blockIdx.x;
  int c = threadIdx.x;
  sp[c] = pooled[r * 128 + c];
  __syncthreads();
  float acc = 0.f;
  for (int k = 0; k < 128; ++k) acc += sp[k] * W1[c * 128 + k];
  acc += b1[c];
  sh1[c] = acc > 0.f ? acc : 0.f;
  __syncthreads();
  if (c < NC) {
    float o = 0.f;
    for (int k = 0; k < 128; ++k) o += sh1[k] * W2[c * 128 + k];
    out[r * NC + c] = o + b2[c];
  }
}

extern "C" void kernel_launch(void* const* d_in, const int* in_sizes, int n_in,
                              void* d_out, int out_size, void* d_ws, size_t ws_size,
                              hipStream_t stream) {
  const int* node_ids = (const int*)d_in[0];
  const int* edge_index = (const int*)d_in[1];
  const int* batch = (const int*)d_in[2];
  const float* emb = (const float*)d_in[3];
  const float* in_W1 = (const float*)d_in[4];
  const float* in_b1 = (const float*)d_in[5];
  const float* in_W2 = (const float*)d_in[6];
  const float* in_b2 = (const float*)d_in[7];
  const float* bn_gamma = (const float*)d_in[8];
  const float* bn_beta = (const float*)d_in[9];
  const float* bn_mean = (const float*)d_in[10];
  const float* bn_var = (const float*)d_in[11];
  const float* out_W1 = (const float*)d_in[12];
  const float* out_b1 = (const float*)d_in[13];
  const float* out_W2 = (const float*)d_in[14];
  const float* out_b2 = (const float*)d_in[15];
  const float* fc1_W = (const float*)d_in[16];
  const float* fc1_b = (const float*)d_in[17];
  const float* fc2_W = (const float*)d_in[18];
  const float* fc2_b = (const float*)d_in[19];
  float* out = (float*)d_out;

  char* ws = (char*)d_ws;
  size_t off = 0;
  auto alloc = [&](size_t bytes) {
    char* p = ws + off;
    off = (off + bytes + 255) & ~(size_t)255;
    return p;
  };
  unsigned short* xb = (unsigned short*)alloc((size_t)NN * 128 * 2);
  unsigned short* hb = (unsigned short*)alloc((size_t)NN * 128 * 2);
  unsigned short* srclist = (unsigned short*)alloc((size_t)NN * CAP * 2);
  int* cnt = (int*)alloc((size_t)NN * 4);
  unsigned short* W1b = (unsigned short*)alloc(128 * 128 * 2);
  unsigned short* W2b = (unsigned short*)alloc(128 * 128 * 2);
  unsigned short* oW1b = (unsigned short*)alloc(128 * 128 * 2);
  unsigned short* oW2b = (unsigned short*)alloc(128 * 128 * 2);
  float* bnscale = (float*)alloc(128 * 4);
  float* bnshift = (float*)alloc(128 * 4);
  float* pooled = (float*)alloc(NG * 128 * 4);

  hipMemsetAsync(cnt, 0, (size_t)NN * 4, stream);
  hipMemsetAsync(pooled, 0, (size_t)NG * 128 * 4, stream);

  prep_kernel<<<64, 256, 0, stream>>>(in_W1, in_W2, out_W1, out_W2,
                                      bn_gamma, bn_beta, bn_mean, bn_var,
                                      W1b, W2b, oW1b, oW2b, bnscale, bnshift);
  int chunks = (NE + 255) / 256;
  fill_kernel<<<chunks * XG, 256, 0, stream>>>(edge_index, cnt, srclist);
  embed_kernel<<<(NN * 32 + 255) / 256, 256, 0, stream>>>(node_ids, emb, xb);

  int mlp_blocks = (NN + 63) / 64;
  const unsigned short* cur = xb;
  unsigned short* nxt = hb;
  for (int l = 0; l < 6; ++l) {
    const unsigned short* w1 = (l < 5) ? W1b : oW1b;
    const unsigned short* w2 = (l < 5) ? W2b : oW2b;
    const float* b1 = (l < 5) ? in_b1 : out_b1;
    const float* b2 = (l < 5) ? in_b2 : out_b2;
    int mode2 = (l < 5) ? 1 : 0;
    int doPool = (l == 5) ? 1 : 0;
    gin_layer_kernel<<<mlp_blocks, 256, 0, stream>>>(
        cur, cnt, srclist, w1, w2, b1, b2, bnscale, bnshift,
        nxt, batch, pooled, NN, mode2, doPool);
    const unsigned short* t = cur;
    cur = nxt;
    nxt = (unsigned short*)t;
  }

  fc_kernel<<<NG, 128, 0, stream>>>(pooled, fc1_W, fc1_b, fc2_W, fc2_b, out);
}

// Round 9
// 488.489 us; speedup vs baseline: 1.2984x; 1.0872x over previous
//
#include <hip/hip_runtime.h>

#define NN 50000
#define NE 800000
#define NG 128
#define NC 41
#define CAP 64
#define XG 8            // XCD groups for fill partitioning
#define RNG 6250        // NN / XG

typedef __attribute__((ext_vector_type(8))) short bfrag8;
typedef __attribute__((ext_vector_type(4))) float facc4;

__device__ __forceinline__ float bf2f(unsigned short u) {
  union { unsigned int i; float f; } v; v.i = ((unsigned int)u) << 16; return v.f;
}
__device__ __forceinline__ unsigned short f2bf(float f) {
  union { float f; unsigned int i; } v; v.f = f;
  unsigned int x = v.i;
  x += 0x7fffu + ((x >> 16) & 1u);
  return (unsigned short)(x >> 16);
}
__device__ __forceinline__ void acc_u4(const uint4 u, float* a) {
  union { unsigned int i; float f; } c;
  c.i = u.x << 16;          a[0] += c.f;
  c.i = u.x & 0xffff0000u;  a[1] += c.f;
  c.i = u.y << 16;          a[2] += c.f;
  c.i = u.y & 0xffff0000u;  a[3] += c.f;
  c.i = u.z << 16;          a[4] += c.f;
  c.i = u.z & 0xffff0000u;  a[5] += c.f;
  c.i = u.w << 16;          a[6] += c.f;
  c.i = u.w & 0xffff0000u;  a[7] += c.f;
}
__device__ __forceinline__ unsigned int pack2(float lo, float hi) {
  return (unsigned int)f2bf(lo) | ((unsigned int)f2bf(hi) << 16);
}

// Weights -> bf16, BN affine precompute (applied AFTER relu).
__global__ void prep_kernel(const float* __restrict__ W1, const float* __restrict__ W2,
                            const float* __restrict__ oW1, const float* __restrict__ oW2,
                            const float* __restrict__ gamma, const float* __restrict__ beta,
                            const float* __restrict__ mean, const float* __restrict__ var,
                            unsigned short* W1b, unsigned short* W2b,
                            unsigned short* oW1b, unsigned short* oW2b,
                            float* scale, float* shift) {
  int i = blockIdx.x * 256 + threadIdx.x;
  if (i < 128 * 128) {
    W1b[i] = f2bf(W1[i]);
    W2b[i] = f2bf(W2[i]);
    oW1b[i] = f2bf(oW1[i]);
    oW2b[i] = f2bf(oW2[i]);
  }
  if (i < 128) {
    float s = gamma[i] * rsqrtf(var[i] + 1e-5f);
    scale[i] = s;
    shift[i] = beta[i] - mean[i] * s;
  }
}

// x = emb[node_ids], stored bf16. One thread per 4 feats.
__global__ void embed_kernel(const int* __restrict__ node_ids, const float* __restrict__ emb,
                             unsigned short* __restrict__ xb) {
  int idx = blockIdx.x * 256 + threadIdx.x;
  if (idx >= NN * 32) return;
  int node = idx >> 5, f = (idx & 31) * 4;
  const float4 v = *(const float4*)&emb[node_ids[node] * 128 + f];
  ushort4 o;
  o.x = f2bf(v.x); o.y = f2bf(v.y); o.z = f2bf(v.z); o.w = f2bf(v.w);
  *(ushort4*)&xb[node * 128 + f] = o;
}

// XCD-partitioned edge bucketing (r0 form): block b -> group g=b&7, chunk
// s=b>>3; group g commits only dst in [g*RNG,(g+1)*RNG) -> srclist/cnt slices
// stay L2-local per XCD.
__global__ __launch_bounds__(256) void fill_kernel(const int* __restrict__ ei,
                                                   int* __restrict__ cnt,
                                                   unsigned short* __restrict__ srclist) {
  int b = blockIdx.x;
  int g = b & 7;
  int s = b >> 3;
  int e = s * 256 + threadIdx.x;
  if (e >= NE) return;
  int d = ei[NE + e];
  unsigned int lo = g * RNG;
  if ((unsigned int)(d - lo) < (unsigned int)RNG) {
    int src = ei[e];
    int pos = atomicAdd(&cnt[d], 1);
    if (pos < CAP) srclist[d * CAP + pos] = (unsigned short)src;
  }
}

// Fused GIN layer (r9 = wave-independent pipeline):
//  - r7/r8: W2 reg-prefetch spills regardless of launch_bounds -> abandoned.
//  - Diagnosis of the 68us floor: gather (~35us, MSHR-bound, VALU idle) and
//    MLP (~33us, compute, memory idle) are forced into BLOCK lockstep by the
//    post-gather barrier -> all resident blocks gather together, then all
//    MFMA together; time = sum not max.
//  - Fix: stage BOTH W1,W2 into LDS up front (80KB -> 2 blocks/CU; r1 showed
//    gather BW is wave-count-insensitive), ONE barrier, then each wave owns
//    its 16 rows end-to-end with no further barriers: gather -> GEMM1 ->
//    GEMM2 -> epilogue -> writeback/pool. All sA traffic is wave-private
//    16-row bands; sW1/sW2 are read-only after the barrier. Waves de-phase
//    naturally -> gather of some waves overlaps MFMA of others on the CU.
__global__ __launch_bounds__(256, 2) void gin_layer_kernel(
    const unsigned short* __restrict__ xin,
    const int* __restrict__ cnt,
    const unsigned short* __restrict__ srclist,
    const unsigned short* __restrict__ W1b,
    const unsigned short* __restrict__ W2b,
    const float* __restrict__ bias1,
    const float* __restrict__ bias2,
    const float* __restrict__ scale,
    const float* __restrict__ shift,
    unsigned short* __restrict__ Out,
    const int* __restrict__ batch,
    float* __restrict__ pooled,
    int M, int mode, int doPool) {
  __shared__ unsigned short sW1[128 * 128];  // 32KB
  __shared__ unsigned short sW2[128 * 128];  // 32KB
  __shared__ unsigned short sA[64 * 128];    // 16KB
  int tid = threadIdx.x;
  int bRow = blockIdx.x * 64;
  int wave = tid >> 6;
  int lane = tid & 63;

  // Stage W1 and W2 cooperatively; the ONLY block barrier follows.
  const uint4* gw1 = (const uint4*)W1b;
  const uint4* gw2 = (const uint4*)W2b;
#pragma unroll
  for (int p = 0; p < 8; ++p) {
    int g = p * 256 + tid;
    int r = g >> 4, b = g & 15;
    int ph = (b + r) & 15;
    *(uint4*)&sW1[(r * 16 + ph) * 8] = gw1[g];
    *(uint4*)&sW2[(r * 16 + ph) * 8] = gw2[g];
  }
  __syncthreads();   // sW1/sW2 ready; everything below is wave-private.

  // ---- Per-wave gather: 16 lanes/node, 4 nodes/pass, 4 passes = own 16 rows
  {
    int al16 = lane & 15;
    int sub4 = lane >> 4;        // 0..3
    int f = al16 * 8;

    int n0 = bRow + wave * 16 + sub4;
    int n1 = n0 + 4, n2 = n0 + 8, n3 = n0 + 12;
    int d0 = (n0 < M) ? cnt[n0] : 0;
    int d1 = (n1 < M) ? cnt[n1] : 0;
    int d2 = (n2 < M) ? cnt[n2] : 0;
    int d3 = (n3 < M) ? cnt[n3] : 0;

#pragma unroll 1
    for (int g = 0; g < 4; ++g) {
      int r = wave * 16 + g * 4 + sub4;   // own band row
      int node = bRow + r;
      float a[8];
      a[0]=0.f; a[1]=0.f; a[2]=0.f; a[3]=0.f;
      a[4]=0.f; a[5]=0.f; a[6]=0.f; a[7]=0.f;
      if (node < M) {
        int deg = (g == 0) ? d0 : (g == 1) ? d1 : (g == 2) ? d2 : d3;
        if (deg > CAP) deg = CAP;
        const unsigned short* lst = &srclist[node * CAP];
        acc_u4(*(const uint4*)&xin[node * 128 + f], a);
        int j = 0;
#pragma unroll 1
        for (; j + 16 <= deg; j += 16) {
          uint4 iv0 = *(const uint4*)&lst[j];
          uint4 iv1 = *(const uint4*)&lst[j + 8];
          int p0 = iv0.x & 0xffff, p1 = iv0.x >> 16;
          int p2 = iv0.y & 0xffff, p3 = iv0.y >> 16;
          int p4 = iv0.z & 0xffff, p5 = iv0.z >> 16;
          int p6 = iv0.w & 0xffff, p7 = iv0.w >> 16;
          uint4 uA0 = *(const uint4*)&xin[p0 * 128 + f];
          uint4 uA1 = *(const uint4*)&xin[p1 * 128 + f];
          uint4 uA2 = *(const uint4*)&xin[p2 * 128 + f];
          uint4 uA3 = *(const uint4*)&xin[p3 * 128 + f];
          uint4 uA4 = *(const uint4*)&xin[p4 * 128 + f];
          uint4 uA5 = *(const uint4*)&xin[p5 * 128 + f];
          uint4 uA6 = *(const uint4*)&xin[p6 * 128 + f];
          uint4 uA7 = *(const uint4*)&xin[p7 * 128 + f];
          int q0 = iv1.x & 0xffff, q1 = iv1.x >> 16;
          int q2 = iv1.y & 0xffff, q3 = iv1.y >> 16;
          int q4 = iv1.z & 0xffff, q5 = iv1.z >> 16;
          int q6 = iv1.w & 0xffff, q7 = iv1.w >> 16;
          uint4 uB0 = *(const uint4*)&xin[q0 * 128 + f];
          uint4 uB1 = *(const uint4*)&xin[q1 * 128 + f];
          uint4 uB2 = *(const uint4*)&xin[q2 * 128 + f];
          uint4 uB3 = *(const uint4*)&xin[q3 * 128 + f];
          uint4 uB4 = *(const uint4*)&xin[q4 * 128 + f];
          uint4 uB5 = *(const uint4*)&xin[q5 * 128 + f];
          uint4 uB6 = *(const uint4*)&xin[q6 * 128 + f];
          uint4 uB7 = *(const uint4*)&xin[q7 * 128 + f];
          acc_u4(uA0, a); acc_u4(uA1, a); acc_u4(uA2, a); acc_u4(uA3, a);
          acc_u4(uA4, a); acc_u4(uA5, a); acc_u4(uA6, a); acc_u4(uA7, a);
          acc_u4(uB0, a); acc_u4(uB1, a); acc_u4(uB2, a); acc_u4(uB3, a);
          acc_u4(uB4, a); acc_u4(uB5, a); acc_u4(uB6, a); acc_u4(uB7, a);
        }
        if (j + 8 <= deg) {
          uint4 iv = *(const uint4*)&lst[j];
          int p0 = iv.x & 0xffff, p1 = iv.x >> 16;
          int p2 = iv.y & 0xffff, p3 = iv.y >> 16;
          int p4 = iv.z & 0xffff, p5 = iv.z >> 16;
          int p6 = iv.w & 0xffff, p7 = iv.w >> 16;
          uint4 u0 = *(const uint4*)&xin[p0 * 128 + f];
          uint4 u1 = *(const uint4*)&xin[p1 * 128 + f];
          uint4 u2 = *(const uint4*)&xin[p2 * 128 + f];
          uint4 u3 = *(const uint4*)&xin[p3 * 128 + f];
          uint4 u4 = *(const uint4*)&xin[p4 * 128 + f];
          uint4 u5 = *(const uint4*)&xin[p5 * 128 + f];
          uint4 u6 = *(const uint4*)&xin[p6 * 128 + f];
          uint4 u7 = *(const uint4*)&xin[p7 * 128 + f];
          acc_u4(u0, a); acc_u4(u1, a); acc_u4(u2, a); acc_u4(u3, a);
          acc_u4(u4, a); acc_u4(u5, a); acc_u4(u6, a); acc_u4(u7, a);
          j += 8;
        }
        if (j + 4 <= deg) {
          uint2 iv = *(const uint2*)&lst[j];
          int p0 = iv.x & 0xffff, p1 = iv.x >> 16;
          int p2 = iv.y & 0xffff, p3 = iv.y >> 16;
          uint4 u0 = *(const uint4*)&xin[p0 * 128 + f];
          uint4 u1 = *(const uint4*)&xin[p1 * 128 + f];
          uint4 u2 = *(const uint4*)&xin[p2 * 128 + f];
          uint4 u3 = *(const uint4*)&xin[p3 * 128 + f];
          acc_u4(u0, a); acc_u4(u1, a); acc_u4(u2, a); acc_u4(u3, a);
          j += 4;
        }
        for (; j < deg; ++j) {
          uint4 u = *(const uint4*)&xin[(int)lst[j] * 128 + f];
          acc_u4(u, a);
        }
      }
      int ph = (al16 + r) & 15;
      uint4 o;
      o.x = pack2(a[0], a[1]); o.y = pack2(a[2], a[3]);
      o.z = pack2(a[4], a[5]); o.w = pack2(a[6], a[7]);
      *(uint4*)&sA[(r * 16 + ph) * 8] = o;
    }
  }
  // No barrier: this wave's sA band is complete; GEMMs below read only it.

  int l16 = lane & 15;
  int quad = lane >> 4;
  int arow = wave * 16 + l16;

  // ---- GEMM1 (A from own band, B from read-only sW1) ----
  {
    bfrag8 af[4];
#pragma unroll
    for (int k = 0; k < 4; ++k) {
      int ph = (k * 4 + quad + arow) & 15;
      af[k] = *(const bfrag8*)&sA[(arow * 16 + ph) * 8];
    }
    facc4 acc[8];
#pragma unroll
    for (int t = 0; t < 8; ++t) acc[t] = (facc4){0.f, 0.f, 0.f, 0.f};
#pragma unroll
    for (int k = 0; k < 4; ++k) {
#pragma unroll
      for (int t = 0; t < 8; ++t) {
        int r = t * 16 + l16;
        int ph = (k * 4 + quad + r) & 15;
        bfrag8 bf = *(const bfrag8*)&sW1[(r * 16 + ph) * 8];
        acc[t] = __builtin_amdgcn_mfma_f32_16x16x32_bf16(af[k], bf, acc[t], 0, 0, 0);
      }
    }
#pragma unroll
    for (int t = 0; t < 8; ++t) {
      int col = t * 16 + l16;
      float b = bias1[col];
      int cb = col >> 3, ce = col & 7;
#pragma unroll
      for (int i = 0; i < 4; ++i) {
        int row = wave * 16 + quad * 4 + i;   // own band
        float v = acc[t][i] + b;
        int ph = (cb + row) & 15;
        sA[(row * 16 + ph) * 8 + ce] = f2bf(v > 0.f ? v : 0.f);
      }
    }
  }
  // No barrier: wave-private handoff.

  // ---- GEMM2 (B from read-only sW2) ----
  {
    bfrag8 af[4];
#pragma unroll
    for (int k = 0; k < 4; ++k) {
      int ph = (k * 4 + quad + arow) & 15;
      af[k] = *(const bfrag8*)&sA[(arow * 16 + ph) * 8];
    }
    facc4 acc[8];
#pragma unroll
    for (int t = 0; t < 8; ++t) acc[t] = (facc4){0.f, 0.f, 0.f, 0.f};
#pragma unroll
    for (int k = 0; k < 4; ++k) {
#pragma unroll
      for (int t = 0; t < 8; ++t) {
        int r = t * 16 + l16;
        int ph = (k * 4 + quad + r) & 15;
        bfrag8 bf = *(const bfrag8*)&sW2[(r * 16 + ph) * 8];
        acc[t] = __builtin_amdgcn_mfma_f32_16x16x32_bf16(af[k], bf, acc[t], 0, 0, 0);
      }
    }
#pragma unroll
    for (int t = 0; t < 8; ++t) {
      int col = t * 16 + l16;
      float b = bias2[col];
      float sc = 1.f, sh = 0.f;
      if (mode == 1) { sc = scale[col]; sh = shift[col]; }
      int cb = col >> 3, ce = col & 7;
#pragma unroll
      for (int i = 0; i < 4; ++i) {
        int row = wave * 16 + quad * 4 + i;   // own band
        float v = acc[t][i] + b;
        v = v > 0.f ? v : 0.f;
        if (mode == 1) v = v * sc + sh;
        int ph = (cb + row) & 15;
        sA[(row * 16 + ph) * 8 + ce] = f2bf(v);
      }
    }
  }
  // No barrier: epilogue below reads only this wave's band.

  if (doPool) {
    // Per-wave segment-sum of own 16 rows by graph id (batch sorted).
    // 64 lanes x 2 cols each cover 128 feats.
#pragma unroll
    for (int cc = 0; cc < 2; ++cc) {
      int fcol = lane + cc * 64;
      int cb = fcol >> 3, ce = fcol & 7;
      float acc = 0.f;
      int cur = -1;
      for (int s = 0; s < 16; ++s) {
        int r = wave * 16 + s;
        int row = bRow + r;
        if (row >= M) break;
        int b = batch[row];
        if (b != cur) {
          if (cur >= 0) atomicAdd(&pooled[cur * 128 + fcol], acc);
          cur = b;
          acc = 0.f;
        }
        int ph = (cb + r) & 15;
        acc += bf2f(sA[(r * 16 + ph) * 8 + ce]);
      }
      if (cur >= 0) atomicAdd(&pooled[cur * 128 + fcol], acc);
    }
  } else {
    // Per-wave writeback of own 16 rows.
#pragma unroll
    for (int p = 0; p < 4; ++p) {
      int r = wave * 16 + p * 4 + (lane >> 4);
      int b = lane & 15;
      int ph = (b + r) & 15;
      int grow = bRow + r;
      if (grow < M)
        *(uint4*)&Out[grow * 128 + b * 8] = *(const uint4*)&sA[(r * 16 + ph) * 8];
    }
  }
}

// Fused head: h1 = relu(pooled[r]@fc1_W^T+b1) in LDS, then out[r] = h1@fc2_W^T+b2.
__global__ __launch_bounds__(128) void fc_kernel(const float* __restrict__ pooled,
                                                 const float* __restrict__ W1,
                                                 const float* __restrict__ b1,
                                                 const float* __restrict__ W2,
                                                 const float* __restrict__ b2,
                                                 float* __restrict__ out) {
  __shared__ float sh1[128];
  __shared__ float sp[128];
  int r = blockIdx.x;
  int c = threadIdx.x;
  sp[c] = pooled[r * 128 + c];
  __syncthreads();
  float acc = 0.f;
  for (int k = 0; k < 128; ++k) acc += sp[k] * W1[c * 128 + k];
  acc += b1[c];
  sh1[c] = acc > 0.f ? acc : 0.f;
  __syncthreads();
  if (c < NC) {
    float o = 0.f;
    for (int k = 0; k < 128; ++k) o += sh1[k] * W2[c * 128 + k];
    out[r * NC + c] = o + b2[c];
  }
}

extern "C" void kernel_launch(void* const* d_in, const int* in_sizes, int n_in,
                              void* d_out, int out_size, void* d_ws, size_t ws_size,
                              hipStream_t stream) {
  const int* node_ids = (const int*)d_in[0];
  const int* edge_index = (const int*)d_in[1];
  const int* batch = (const int*)d_in[2];
  const float* emb = (const float*)d_in[3];
  const float* in_W1 = (const float*)d_in[4];
  const float* in_b1 = (const float*)d_in[5];
  const float* in_W2 = (const float*)d_in[6];
  const float* in_b2 = (const float*)d_in[7];
  const float* bn_gamma = (const float*)d_in[8];
  const float* bn_beta = (const float*)d_in[9];
  const float* bn_mean = (const float*)d_in[10];
  const float* bn_var = (const float*)d_in[11];
  const float* out_W1 = (const float*)d_in[12];
  const float* out_b1 = (const float*)d_in[13];
  const float* out_W2 = (const float*)d_in[14];
  const float* out_b2 = (const float*)d_in[15];
  const float* fc1_W = (const float*)d_in[16];
  const float* fc1_b = (const float*)d_in[17];
  const float* fc2_W = (const float*)d_in[18];
  const float* fc2_b = (const float*)d_in[19];
  float* out = (float*)d_out;

  char* ws = (char*)d_ws;
  size_t off = 0;
  auto alloc = [&](size_t bytes) {
    char* p = ws + off;
    off = (off + bytes + 255) & ~(size_t)255;
    return p;
  };
  unsigned short* xb = (unsigned short*)alloc((size_t)NN * 128 * 2);
  unsigned short* hb = (unsigned short*)alloc((size_t)NN * 128 * 2);
  unsigned short* srclist = (unsigned short*)alloc((size_t)NN * CAP * 2);
  int* cnt = (int*)alloc((size_t)NN * 4);
  unsigned short* W1b = (unsigned short*)alloc(128 * 128 * 2);
  unsigned short* W2b = (unsigned short*)alloc(128 * 128 * 2);
  unsigned short* oW1b = (unsigned short*)alloc(128 * 128 * 2);
  unsigned short* oW2b = (unsigned short*)alloc(128 * 128 * 2);
  float* bnscale = (float*)alloc(128 * 4);
  float* bnshift = (float*)alloc(128 * 4);
  float* pooled = (float*)alloc(NG * 128 * 4);

  hipMemsetAsync(cnt, 0, (size_t)NN * 4, stream);
  hipMemsetAsync(pooled, 0, (size_t)NG * 128 * 4, stream);

  prep_kernel<<<64, 256, 0, stream>>>(in_W1, in_W2, out_W1, out_W2,
                                      bn_gamma, bn_beta, bn_mean, bn_var,
                                      W1b, W2b, oW1b, oW2b, bnscale, bnshift);
  int chunks = (NE + 255) / 256;
  fill_kernel<<<chunks * XG, 256, 0, stream>>>(edge_index, cnt, srclist);
  embed_kernel<<<(NN * 32 + 255) / 256, 256, 0, stream>>>(node_ids, emb, xb);

  int mlp_blocks = (NN + 63) / 64;
  const unsigned short* cur = xb;
  unsigned short* nxt = hb;
  for (int l = 0; l < 6; ++l) {
    const unsigned short* w1 = (l < 5) ? W1b : oW1b;
    const unsigned short* w2 = (l < 5) ? W2b : oW2b;
    const float* b1 = (l < 5) ? in_b1 : out_b1;
    const float* b2 = (l < 5) ? in_b2 : out_b2;
    int mode2 = (l < 5) ? 1 : 0;
    int doPool = (l == 5) ? 1 : 0;
    gin_layer_kernel<<<mlp_blocks, 256, 0, stream>>>(
        cur, cnt, srclist, w1, w2, b1, b2, bnscale, bnshift,
        nxt, batch, pooled, NN, mode2, doPool);
    const unsigned short* t = cur;
    cur = nxt;
    nxt = (unsigned short*)t;
  }

  fc_kernel<<<NG, 128, 0, stream>>>(pooled, fc1_W, fc1_b, fc2_W, fc2_b, out);
}

// Round 10
// 485.751 us; speedup vs baseline: 1.3057x; 1.0056x over previous
//
#include <hip/hip_runtime.h>

#define NN 50000
#define NE 800000
#define NG 128
#define NC 41
#define CAP 64
#define XG 8            // XCD groups for fill partitioning
#define RNG 6250        // NN / XG

typedef __attribute__((ext_vector_type(8))) short bfrag8;
typedef __attribute__((ext_vector_type(4))) float facc4;

__device__ __forceinline__ float bf2f(unsigned short u) {
  union { unsigned int i; float f; } v; v.i = ((unsigned int)u) << 16; return v.f;
}
__device__ __forceinline__ unsigned short f2bf(float f) {
  union { float f; unsigned int i; } v; v.f = f;
  unsigned int x = v.i;
  x += 0x7fffu + ((x >> 16) & 1u);
  return (unsigned short)(x >> 16);
}
__device__ __forceinline__ void acc_u4(const uint4 u, float* a) {
  union { unsigned int i; float f; } c;
  c.i = u.x << 16;          a[0] += c.f;
  c.i = u.x & 0xffff0000u;  a[1] += c.f;
  c.i = u.y << 16;          a[2] += c.f;
  c.i = u.y & 0xffff0000u;  a[3] += c.f;
  c.i = u.z << 16;          a[4] += c.f;
  c.i = u.z & 0xffff0000u;  a[5] += c.f;
  c.i = u.w << 16;          a[6] += c.f;
  c.i = u.w & 0xffff0000u;  a[7] += c.f;
}
__device__ __forceinline__ unsigned int pack2(float lo, float hi) {
  return (unsigned int)f2bf(lo) | ((unsigned int)f2bf(hi) << 16);
}

// Weights -> bf16, BN affine precompute (applied AFTER relu).
__global__ void prep_kernel(const float* __restrict__ W1, const float* __restrict__ W2,
                            const float* __restrict__ oW1, const float* __restrict__ oW2,
                            const float* __restrict__ gamma, const float* __restrict__ beta,
                            const float* __restrict__ mean, const float* __restrict__ var,
                            unsigned short* W1b, unsigned short* W2b,
                            unsigned short* oW1b, unsigned short* oW2b,
                            float* scale, float* shift) {
  int i = blockIdx.x * 256 + threadIdx.x;
  if (i < 128 * 128) {
    W1b[i] = f2bf(W1[i]);
    W2b[i] = f2bf(W2[i]);
    oW1b[i] = f2bf(oW1[i]);
    oW2b[i] = f2bf(oW2[i]);
  }
  if (i < 128) {
    float s = gamma[i] * rsqrtf(var[i] + 1e-5f);
    scale[i] = s;
    shift[i] = beta[i] - mean[i] * s;
  }
}

// x = emb[node_ids], stored bf16. One thread per 4 feats.
__global__ void embed_kernel(const int* __restrict__ node_ids, const float* __restrict__ emb,
                             unsigned short* __restrict__ xb) {
  int idx = blockIdx.x * 256 + threadIdx.x;
  if (idx >= NN * 32) return;
  int node = idx >> 5, f = (idx & 31) * 4;
  const float4 v = *(const float4*)&emb[node_ids[node] * 128 + f];
  ushort4 o;
  o.x = f2bf(v.x); o.y = f2bf(v.y); o.z = f2bf(v.z); o.w = f2bf(v.w);
  *(ushort4*)&xb[node * 128 + f] = o;
}

// XCD-partitioned edge bucketing: block b -> group g=b&7, chunk s=b>>3;
// group g commits only dst in [g*RNG,(g+1)*RNG) -> srclist/cnt slices stay
// L2-local per XCD (kills cross-XCD 64B-line ping-pong).
__global__ __launch_bounds__(256) void fill_kernel(const int* __restrict__ ei,
                                                   int* __restrict__ cnt,
                                                   unsigned short* __restrict__ srclist) {
  int b = blockIdx.x;
  int g = b & 7;
  int s = b >> 3;
  int e = s * 256 + threadIdx.x;
  if (e >= NE) return;
  int d = ei[NE + e];
  unsigned int lo = g * RNG;
  if ((unsigned int)(d - lo) < (unsigned int)RNG) {
    int src = ei[e];
    int pos = atomicAdd(&cnt[d], 1);
    if (pos < CAP) srclist[d * CAP + pos] = (unsigned short)src;
  }
}

// Fused GIN layer (final = r1/best-of-session, 482.2us measured):
// per 64-row tile, aggregate h = x + sum_{nbrs} x directly into the swizzled
// sA LDS tile (W1 staging loads issued first to overlap gather latency), then
// Out = ep2(relu(relu(h@W1^T+b1)@W2^T+b2)) with optional BN affine.
// Last layer (doPool): segment-sum rows by batch straight out of LDS.
// 48KB LDS -> 3 blocks/CU.
//
// Session ledger (why this is the floor): gather = per-CU vector-memory
// throughput wall (~9 B/cy/CU ~= m13 ceiling). Null/negative axes:
// occupancy x1.5 (r1-var), window depth x2 (r3), locality (r2/r4: FETCH
// 80->51MB but slower), W2 reg-prefetch (r7/r8: spills), wave-async overlap
// (r9: -7%). Edge traffic 205MB/layer is compulsory at bf16.
__global__ __launch_bounds__(256) void gin_layer_kernel(
    const unsigned short* __restrict__ xin,
    const int* __restrict__ cnt,
    const unsigned short* __restrict__ srclist,
    const unsigned short* __restrict__ W1b,
    const unsigned short* __restrict__ W2b,
    const float* __restrict__ bias1,
    const float* __restrict__ bias2,
    const float* __restrict__ scale,
    const float* __restrict__ shift,
    unsigned short* __restrict__ Out,
    const int* __restrict__ batch,
    float* __restrict__ pooled,
    int M, int mode, int doPool) {
  __shared__ unsigned short sW[128 * 128];   // 32KB: W1, then W2
  __shared__ unsigned short sA[64 * 128];    // 16KB
  int tid = threadIdx.x;
  int bRow = blockIdx.x * 64;

  // Stage W1 first: loads issued early so they overlap gather latency.
  const uint4* gw1 = (const uint4*)W1b;
#pragma unroll
  for (int p = 0; p < 8; ++p) {
    int g = p * 256 + tid;
    int r = g >> 4, b = g & 15;
    int ph = (b + r) & 15;
    *(uint4*)&sW[(r * 16 + ph) * 8] = gw1[g];
  }

  // ---- Fused aggregation: 16 lanes/node, 16 nodes/pass, 4 passes ----
  {
    int al16 = tid & 15;
    int sub = tid >> 4;          // 0..15
    int f = al16 * 8;
#pragma unroll 1
    for (int g = 0; g < 4; ++g) {
      int r = g * 16 + sub;      // tile row 0..63
      int node = bRow + r;
      float a[8];
      a[0]=0.f; a[1]=0.f; a[2]=0.f; a[3]=0.f;
      a[4]=0.f; a[5]=0.f; a[6]=0.f; a[7]=0.f;
      if (node < M) {
        acc_u4(*(const uint4*)&xin[node * 128 + f], a);
        int deg = cnt[node];
        if (deg > CAP) deg = CAP;
        const unsigned short* lst = &srclist[node * CAP];
        int j = 0;
        for (; j + 8 <= deg; j += 8) {
          uint4 u0 = *(const uint4*)&xin[(int)lst[j] * 128 + f];
          uint4 u1 = *(const uint4*)&xin[(int)lst[j + 1] * 128 + f];
          uint4 u2 = *(const uint4*)&xin[(int)lst[j + 2] * 128 + f];
          uint4 u3 = *(const uint4*)&xin[(int)lst[j + 3] * 128 + f];
          uint4 u4 = *(const uint4*)&xin[(int)lst[j + 4] * 128 + f];
          uint4 u5 = *(const uint4*)&xin[(int)lst[j + 5] * 128 + f];
          uint4 u6 = *(const uint4*)&xin[(int)lst[j + 6] * 128 + f];
          uint4 u7 = *(const uint4*)&xin[(int)lst[j + 7] * 128 + f];
          acc_u4(u0, a); acc_u4(u1, a); acc_u4(u2, a); acc_u4(u3, a);
          acc_u4(u4, a); acc_u4(u5, a); acc_u4(u6, a); acc_u4(u7, a);
        }
        for (; j + 4 <= deg; j += 4) {
          uint4 u0 = *(const uint4*)&xin[(int)lst[j] * 128 + f];
          uint4 u1 = *(const uint4*)&xin[(int)lst[j + 1] * 128 + f];
          uint4 u2 = *(const uint4*)&xin[(int)lst[j + 2] * 128 + f];
          uint4 u3 = *(const uint4*)&xin[(int)lst[j + 3] * 128 + f];
          acc_u4(u0, a); acc_u4(u1, a); acc_u4(u2, a); acc_u4(u3, a);
        }
        for (; j < deg; ++j) {
          uint4 u = *(const uint4*)&xin[(int)lst[j] * 128 + f];
          acc_u4(u, a);
        }
      }
      int ph = (al16 + r) & 15;
      uint4 o;
      o.x = pack2(a[0], a[1]); o.y = pack2(a[2], a[3]);
      o.z = pack2(a[4], a[5]); o.w = pack2(a[6], a[7]);
      *(uint4*)&sA[(r * 16 + ph) * 8] = o;
    }
  }
  __syncthreads();

  int wave = tid >> 6;
  int lane = tid & 63;
  int l16 = lane & 15;
  int quad = lane >> 4;
  int arow = wave * 16 + l16;

  // ---- GEMM1 ----
  {
    bfrag8 af[4];
#pragma unroll
    for (int k = 0; k < 4; ++k) {
      int ph = (k * 4 + quad + arow) & 15;
      af[k] = *(const bfrag8*)&sA[(arow * 16 + ph) * 8];
    }
    facc4 acc[8];
#pragma unroll
    for (int t = 0; t < 8; ++t) acc[t] = (facc4){0.f, 0.f, 0.f, 0.f};
#pragma unroll
    for (int k = 0; k < 4; ++k) {
#pragma unroll
      for (int t = 0; t < 8; ++t) {
        int r = t * 16 + l16;
        int ph = (k * 4 + quad + r) & 15;
        bfrag8 bf = *(const bfrag8*)&sW[(r * 16 + ph) * 8];
        acc[t] = __builtin_amdgcn_mfma_f32_16x16x32_bf16(af[k], bf, acc[t], 0, 0, 0);
      }
    }
#pragma unroll
    for (int t = 0; t < 8; ++t) {
      int col = t * 16 + l16;
      float b = bias1[col];
      int cb = col >> 3, ce = col & 7;
#pragma unroll
      for (int i = 0; i < 4; ++i) {
        int row = wave * 16 + quad * 4 + i;
        float v = acc[t][i] + b;
        int ph = (cb + row) & 15;
        sA[(row * 16 + ph) * 8 + ce] = f2bf(v > 0.f ? v : 0.f);
      }
    }
  }
  __syncthreads();   // all W1 reads done before restage

  const uint4* gw2 = (const uint4*)W2b;
#pragma unroll
  for (int p = 0; p < 8; ++p) {
    int g = p * 256 + tid;
    int r = g >> 4, b = g & 15;
    int ph = (b + r) & 15;
    *(uint4*)&sW[(r * 16 + ph) * 8] = gw2[g];
  }
  __syncthreads();   // W2 staged before GEMM2 reads

  // ---- GEMM2 ----
  {
    bfrag8 af[4];
#pragma unroll
    for (int k = 0; k < 4; ++k) {
      int ph = (k * 4 + quad + arow) & 15;
      af[k] = *(const bfrag8*)&sA[(arow * 16 + ph) * 8];
    }
    facc4 acc[8];
#pragma unroll
    for (int t = 0; t < 8; ++t) acc[t] = (facc4){0.f, 0.f, 0.f, 0.f};
#pragma unroll
    for (int k = 0; k < 4; ++k) {
#pragma unroll
      for (int t = 0; t < 8; ++t) {
        int r = t * 16 + l16;
        int ph = (k * 4 + quad + r) & 15;
        bfrag8 bf = *(const bfrag8*)&sW[(r * 16 + ph) * 8];
        acc[t] = __builtin_amdgcn_mfma_f32_16x16x32_bf16(af[k], bf, acc[t], 0, 0, 0);
      }
    }
#pragma unroll
    for (int t = 0; t < 8; ++t) {
      int col = t * 16 + l16;
      float b = bias2[col];
      float sc = 1.f, sh = 0.f;
      if (mode == 1) { sc = scale[col]; sh = shift[col]; }
      int cb = col >> 3, ce = col & 7;
#pragma unroll
      for (int i = 0; i < 4; ++i) {
        int row = wave * 16 + quad * 4 + i;
        float v = acc[t][i] + b;
        v = v > 0.f ? v : 0.f;
        if (mode == 1) v = v * sc + sh;
        int ph = (cb + row) & 15;
        sA[(row * 16 + ph) * 8 + ce] = f2bf(v);
      }
    }
  }
  __syncthreads();

  if (doPool) {
    // Last layer: segment-sum this tile's rows by graph id straight out of
    // LDS (batch sorted -> at most a couple of run breaks per 64-row tile).
    if (tid < 128) {
      int fcol = tid;
      int cb = fcol >> 3, ce = fcol & 7;
      float acc = 0.f;
      int cur = -1;
      for (int r = 0; r < 64; ++r) {
        int row = bRow + r;
        if (row >= M) break;
        int b = batch[row];
        if (b != cur) {
          if (cur >= 0) atomicAdd(&pooled[cur * 128 + fcol], acc);
          cur = b;
          acc = 0.f;
        }
        int ph = (cb + r) & 15;
        acc += bf2f(sA[(r * 16 + ph) * 8 + ce]);
      }
      if (cur >= 0) atomicAdd(&pooled[cur * 128 + fcol], acc);
    }
  } else {
#pragma unroll
    for (int p = 0; p < 4; ++p) {
      int g = p * 256 + tid;
      int r = g >> 4, b = g & 15;
      int ph = (b + r) & 15;
      int grow = bRow + r;
      if (grow < M)
        *(uint4*)&Out[grow * 128 + b * 8] = *(const uint4*)&sA[(r * 16 + ph) * 8];
    }
  }
}

// Fused head: h1 = relu(pooled[r]@fc1_W^T+b1) in LDS, then out[r] = h1@fc2_W^T+b2.
__global__ __launch_bounds__(128) void fc_kernel(const float* __restrict__ pooled,
                                                 const float* __restrict__ W1,
                                                 const float* __restrict__ b1,
                                                 const float* __restrict__ W2,
                                                 const float* __restrict__ b2,
                                                 float* __restrict__ out) {
  __shared__ float sh1[128];
  __shared__ float sp[128];
  int r = blockIdx.x;
  int c = threadIdx.x;
  sp[c] = pooled[r * 128 + c];
  __syncthreads();
  float acc = 0.f;
  for (int k = 0; k < 128; ++k) acc += sp[k] * W1[c * 128 + k];
  acc += b1[c];
  sh1[c] = acc > 0.f ? acc : 0.f;
  __syncthreads();
  if (c < NC) {
    float o = 0.f;
    for (int k = 0; k < 128; ++k) o += sh1[k] * W2[c * 128 + k];
    out[r * NC + c] = o + b2[c];
  }
}

extern "C" void kernel_launch(void* const* d_in, const int* in_sizes, int n_in,
                              void* d_out, int out_size, void* d_ws, size_t ws_size,
                              hipStream_t stream) {
  const int* node_ids = (const int*)d_in[0];
  const int* edge_index = (const int*)d_in[1];
  const int* batch = (const int*)d_in[2];
  const float* emb = (const float*)d_in[3];
  const float* in_W1 = (const float*)d_in[4];
  const float* in_b1 = (const float*)d_in[5];
  const float* in_W2 = (const float*)d_in[6];
  const float* in_b2 = (const float*)d_in[7];
  const float* bn_gamma = (const float*)d_in[8];
  const float* bn_beta = (const float*)d_in[9];
  const float* bn_mean = (const float*)d_in[10];
  const float* bn_var = (const float*)d_in[11];
  const float* out_W1 = (const float*)d_in[12];
  const float* out_b1 = (const float*)d_in[13];
  const float* out_W2 = (const float*)d_in[14];
  const float* out_b2 = (const float*)d_in[15];
  const float* fc1_W = (const float*)d_in[16];
  const float* fc1_b = (const float*)d_in[17];
  const float* fc2_W = (const float*)d_in[18];
  const float* fc2_b = (const float*)d_in[19];
  float* out = (float*)d_out;

  char* ws = (char*)d_ws;
  size_t off = 0;
  auto alloc = [&](size_t bytes) {
    char* p = ws + off;
    off = (off + bytes + 255) & ~(size_t)255;
    return p;
  };
  unsigned short* xb = (unsigned short*)alloc((size_t)NN * 128 * 2);
  unsigned short* hb = (unsigned short*)alloc((size_t)NN * 128 * 2);
  unsigned short* srclist = (unsigned short*)alloc((size_t)NN * CAP * 2);
  int* cnt = (int*)alloc((size_t)NN * 4);
  unsigned short* W1b = (unsigned short*)alloc(128 * 128 * 2);
  unsigned short* W2b = (unsigned short*)alloc(128 * 128 * 2);
  unsigned short* oW1b = (unsigned short*)alloc(128 * 128 * 2);
  unsigned short* oW2b = (unsigned short*)alloc(128 * 128 * 2);
  float* bnscale = (float*)alloc(128 * 4);
  float* bnshift = (float*)alloc(128 * 4);
  float* pooled = (float*)alloc(NG * 128 * 4);

  hipMemsetAsync(cnt, 0, (size_t)NN * 4, stream);
  hipMemsetAsync(pooled, 0, (size_t)NG * 128 * 4, stream);

  prep_kernel<<<64, 256, 0, stream>>>(in_W1, in_W2, out_W1, out_W2,
                                      bn_gamma, bn_beta, bn_mean, bn_var,
                                      W1b, W2b, oW1b, oW2b, bnscale, bnshift);
  int chunks = (NE + 255) / 256;
  fill_kernel<<<chunks * XG, 256, 0, stream>>>(edge_index, cnt, srclist);
  embed_kernel<<<(NN * 32 + 255) / 256, 256, 0, stream>>>(node_ids, emb, xb);

  int mlp_blocks = (NN + 63) / 64;
  const unsigned short* cur = xb;
  unsigned short* nxt = hb;
  for (int l = 0; l < 6; ++l) {
    const unsigned short* w1 = (l < 5) ? W1b : oW1b;
    const unsigned short* w2 = (l < 5) ? W2b : oW2b;
    const float* b1 = (l < 5) ? in_b1 : out_b1;
    const float* b2 = (l < 5) ? in_b2 : out_b2;
    int mode2 = (l < 5) ? 1 : 0;
    int doPool = (l == 5) ? 1 : 0;
    gin_layer_kernel<<<mlp_blocks, 256, 0, stream>>>(
        cur, cnt, srclist, w1, w2, b1, b2, bnscale, bnshift,
        nxt, batch, pooled, NN, mode2, doPool);
    const unsigned short* t = cur;
    cur = nxt;
    nxt = (unsigned short*)t;
  }

  fc_kernel<<<NG, 128, 0, stream>>>(pooled, fc1_W, fc1_b, fc2_W, fc2_b, out);
}